// Round 13
// baseline (1042.281 us; speedup 1.0000x reference)
//
#include <hip/hip_runtime.h>
#include <cstdint>
#include <cstddef>

#define DIMX 256
#define DIMV 512
#define DIMH 768
#define EPSV 0.05f

typedef __bf16 bf16x8 __attribute__((ext_vector_type(8)));
typedef unsigned short u16x8 __attribute__((ext_vector_type(8)));
typedef unsigned int u32x2 __attribute__((ext_vector_type(2)));
typedef unsigned int u32x4 __attribute__((ext_vector_type(4)));
typedef float f32x4 __attribute__((ext_vector_type(4)));

__device__ __forceinline__ unsigned short f2bf(float f) {
  unsigned int u = __float_as_uint(f);
  u += 0x7fffu + ((u >> 16) & 1u);
  return (unsigned short)(u >> 16);
}
__device__ __forceinline__ float bf2f(unsigned short b) {
  return __uint_as_float(((unsigned int)b) << 16);
}
__device__ __forceinline__ bf16x8 ld8(const unsigned short* p) {
  u16x8 u = *reinterpret_cast<const u16x8*>(p);
  return __builtin_bit_cast(bf16x8, u);
}
__device__ __forceinline__ f32x4 mfma16(bf16x8 a, bf16x8 b, f32x4 c) {
  return __builtin_amdgcn_mfma_f32_16x16x32_bf16(a, b, c, 0, 0, 0);
}
__device__ __forceinline__ float rdlane(float v, int lane) {
  return __uint_as_float(
      (unsigned int)__builtin_amdgcn_readlane((int)__float_as_uint(v), lane));
}

// ---------------- K0: split X into bf16 hi/lo for split-MFMA SYRK ----------------
__global__ void k_split(const float* __restrict__ X, unsigned short* __restrict__ Xhi,
                        unsigned short* __restrict__ Xlo) {
  int idx = blockIdx.x * 256 + threadIdx.x;
  if (idx < DIMH * DIMH) {
    float f = X[idx];
    unsigned short h = f2bf(f);
    Xhi[idx] = h;
    Xlo[idx] = f2bf(f - bf2f(h));
  }
}

// ---------------- K1: P = 0.5*Pstar@Pstar^T + eps*I (fp32, direct) ----------------
__global__ void k_syrkP(const float* __restrict__ A, float* __restrict__ P) {
  int bi = blockIdx.x >> 4, bj = blockIdx.x & 15;
  int ty = threadIdx.x >> 4, tx = threadIdx.x & 15;
  int i = bi * 16 + ty, j = bj * 16 + tx;
  const f32x4* ra = reinterpret_cast<const f32x4*>(A + (size_t)i * DIMX);
  const f32x4* rb = reinterpret_cast<const f32x4*>(A + (size_t)j * DIMX);
  float s = 0.f;
  for (int k = 0; k < 64; ++k) {
    f32x4 a = ra[k], b = rb[k];
    s = fmaf(a[0], b[0], s); s = fmaf(a[1], b[1], s);
    s = fmaf(a[2], b[2], s); s = fmaf(a[3], b[3], s);
  }
  P[(size_t)i * DIMX + j] = 0.5f * s + (i == j ? EPSV : 0.f);
}

// ---------------- K2: H = X@X^T + eps*I via bf16x2 split MFMA ----------------
__global__ __launch_bounds__(256) void k_syrkH(const unsigned short* __restrict__ Xhi,
                                               const unsigned short* __restrict__ Xlo,
                                               float* __restrict__ H) {
  int bx = blockIdx.x % 12, by = blockIdx.x / 12;
  int i0 = by * 64, j0 = bx * 64;
  int l = threadIdx.x & 63, wv = threadIdx.x >> 6;
  int lr = l & 15, lq = l >> 4;
  int koff = lq * 8;
  int arow = i0 + wv * 16 + lr;
  f32x4 z = {0.f, 0.f, 0.f, 0.f};
  f32x4 acc[4] = {z, z, z, z};
  for (int pass = 0; pass < 3; ++pass) {
    const unsigned short* Xa = (pass == 2) ? Xlo : Xhi;
    const unsigned short* Xb = (pass == 1) ? Xlo : Xhi;
    for (int kc = 0; kc < 24; ++kc) {
      bf16x8 a = ld8(&Xa[(size_t)arow * DIMH + kc * 32 + koff]);
#pragma unroll
      for (int ct = 0; ct < 4; ++ct) {
        bf16x8 b = ld8(&Xb[(size_t)(j0 + ct * 16 + lr) * DIMH + kc * 32 + koff]);
        acc[ct] = mfma16(a, b, acc[ct]);
      }
    }
  }
#pragma unroll
  for (int ct = 0; ct < 4; ++ct)
#pragma unroll
    for (int r = 0; r < 4; ++r) {
      int i = i0 + wv * 16 + lq * 4 + r;
      int j = j0 + ct * 16 + lr;
      H[(size_t)i * DIMH + j] = acc[ct][r] + (i == j ? EPSV : 0.f);
    }
}

// ---------------- K3: blocked Cholesky — 256 threads, readlane-serial core ---------
__global__ __launch_bounds__(256, 1) void k_chol(float* __restrict__ A,
                                                 float* __restrict__ Wbuf) {
  __shared__ float Wl[32][33];
  __shared__ float T[32][232];
  int t = threadIdx.x;
  int wv = t >> 6, l = t & 63;
#pragma unroll 1
  for (int s = 0; s < 8; ++s) {
    int K = 32 * s;
    int R32 = 256 - K - 32;
    if (wv == 0) {
      int li = l & 31;
      float d[32];
#pragma unroll
      for (int j = 0; j < 32; ++j) d[j] = A[(K + j) * 256 + K + li];
#pragma unroll
      for (int k = 0; k < 32; ++k) {
        float dkk = rdlane(d[k], k);
        float ip = rsqrtf(dkk);
        d[k] *= ip;
#pragma unroll
        for (int j = k + 1; j < 32; ++j) {
          float ljk = rdlane(d[k], j);
          d[j] = fmaf(-ljk, d[k], d[j]);
        }
      }
      float wcol[32];
#pragma unroll
      for (int i = 0; i < 32; ++i) {
        float Lii = rdlane(d[i], i);
        float ipi = 1.0f / Lii;
        float acc = (li == i) ? 1.0f : 0.0f;
#pragma unroll
        for (int k = 0; k < i; ++k) {
          float Lik = rdlane(d[k], i);
          acc = fmaf(-Lik, wcol[k], acc);
        }
        wcol[i] = acc * ipi;
      }
      if (l < 32) {
#pragma unroll
        for (int k = 0; k < 32; ++k) {
          Wl[k][l] = wcol[k];
          Wbuf[s * 1024 + k * 32 + l] = wcol[k];
        }
      }
    }
    __syncthreads();
    if (R32 > 0) {
      int nrt = R32 >> 2;
      for (int u = t; u < nrt * 8; u += 256) {
        int rt = u >> 3, jg = u & 7;
        int r = K + 32 + rt * 4;
        int j0 = jg * 4;
        f32x4 z4 = {0.f, 0.f, 0.f, 0.f};
        f32x4 acc[4] = {z4, z4, z4, z4};
#pragma unroll
        for (int k = 0; k < 32; ++k) {
          f32x4 av = *reinterpret_cast<const f32x4*>(&A[(K + k) * 256 + r]);
#pragma unroll
          for (int jj = 0; jj < 4; ++jj) {
            float w = Wl[j0 + jj][k];
            acc[jj][0] = fmaf(av[0], w, acc[jj][0]);
            acc[jj][1] = fmaf(av[1], w, acc[jj][1]);
            acc[jj][2] = fmaf(av[2], w, acc[jj][2]);
            acc[jj][3] = fmaf(av[3], w, acc[jj][3]);
          }
        }
#pragma unroll
        for (int jj = 0; jj < 4; ++jj)
          *reinterpret_cast<f32x4*>(&T[j0 + jj][rt * 4]) = acc[jj];
      }
      __syncthreads();
#pragma unroll 1
      for (int j = 0; j < 32; ++j) {
        int rl = t << 2;
        if (rl < R32)
          *reinterpret_cast<f32x4*>(&A[(K + j) * 256 + K + 32 + rl]) =
              *reinterpret_cast<const f32x4*>(&T[j][rl]);
      }
      int T4 = R32 >> 2;
      int ntile = T4 * (T4 + 1) / 2;
      for (int idx = t; idx < ntile; idx += 256) {
        int ti = (int)((sqrtf(8.0f * (float)idx + 1.0f) - 1.0f) * 0.5f);
        while ((ti + 1) * (ti + 2) / 2 <= idx) ++ti;
        while (ti * (ti + 1) / 2 > idx) --ti;
        int tj = idx - ti * (ti + 1) / 2;
        int gi = K + 32 + 4 * ti, gj = K + 32 + 4 * tj;
        f32x4 acc[4];
#pragma unroll
        for (int jj = 0; jj < 4; ++jj)
          acc[jj] = *reinterpret_cast<const f32x4*>(&A[(gj + jj) * 256 + gi]);
#pragma unroll
        for (int k = 0; k < 32; ++k) {
          f32x4 av = *reinterpret_cast<const f32x4*>(&T[k][4 * ti]);
          f32x4 bv = *reinterpret_cast<const f32x4*>(&T[k][4 * tj]);
#pragma unroll
          for (int jj = 0; jj < 4; ++jj) {
            acc[jj][0] = fmaf(-av[0], bv[jj], acc[jj][0]);
            acc[jj][1] = fmaf(-av[1], bv[jj], acc[jj][1]);
            acc[jj][2] = fmaf(-av[2], bv[jj], acc[jj][2]);
            acc[jj][3] = fmaf(-av[3], bv[jj], acc[jj][3]);
          }
        }
#pragma unroll
        for (int jj = 0; jj < 4; ++jj)
          *reinterpret_cast<f32x4*>(&A[(gj + jj) * 256 + gi]) = acc[jj];
      }
    }
    __syncthreads();
  }
}

// ---------------- K4: Gin[c][q] = [C1 | D11] as bf16 ----------------
__global__ void k_gin(const float* __restrict__ H, const float* __restrict__ Chi,
                      unsigned short* __restrict__ Gin) {
  int q = blockIdx.x * 256 + threadIdx.x;
  int c = blockIdx.y;
  float rlam = 2.f / H[(size_t)(256 + c) * DIMH + 256 + c];
  float v;
  if (q < 256) {
    v = Chi[(size_t)q * DIMV + c] * rlam;
  } else {
    int j = q - 256;
    v = (j < c) ? -H[(size_t)(256 + c) * DIMH + 256 + j] * rlam : 0.f;
  }
  Gin[(size_t)c * DIMH + q] = f2bf(v);
}

// ---------------- K5: Gout = P^{-1}[Y|M] via BLOCK substitution (GEMM-only) --------
__global__ __launch_bounds__(256, 2) void k_gsolve(const float* __restrict__ Lg,
                                                   const float* __restrict__ Wbuf,
                                                   const float* __restrict__ H,
                                                   const float* __restrict__ Y1,
                                                   const float* __restrict__ Chi,
                                                   unsigned short* __restrict__ Gout) {
  __shared__ float Bs[256][33];
  __shared__ float Wl[32][33];
  int t = threadIdx.x, tc = t & 31, rg = t >> 5;
  int q = blockIdx.x * 32 + tc;
#pragma unroll 1
  for (int rr = 0; rr < 32; ++rr) {
    int r = rg * 32 + rr;
    float v;
    if (q < 256) {
      v = -0.5f * (H[(size_t)r * DIMH + q] + Y1[r * 256 + q] - Y1[q * 256 + r]);
    } else {
      int c = q - 256;
      v = -(H[(size_t)r * DIMH + 256 + c] + Chi[r * 512 + c]);
    }
    Bs[r][tc] = v;
  }
  __syncthreads();
  // forward
#pragma unroll 1
  for (int s = 0; s < 8; ++s) {
    for (int idx = t; idx < 1024; idx += 256) Wl[idx >> 5][idx & 31] = Wbuf[s * 1024 + idx];
    __syncthreads();
    float ua[4] = {0.f, 0.f, 0.f, 0.f};
#pragma unroll
    for (int k = 0; k < 32; ++k) {
      float b = Bs[32 * s + k][tc];
#pragma unroll
      for (int rr = 0; rr < 4; ++rr) ua[rr] = fmaf(Wl[rg * 4 + rr][k], b, ua[rr]);
    }
    __syncthreads();
#pragma unroll
    for (int rr = 0; rr < 4; ++rr) Bs[32 * s + rg * 4 + rr][tc] = ua[rr];
    __syncthreads();
#pragma unroll 1
    for (int rb = 32 * (s + 1) + rg * 4; rb < 256; rb += 32) {
      f32x4 acc = {Bs[rb][tc], Bs[rb + 1][tc], Bs[rb + 2][tc], Bs[rb + 3][tc]};
#pragma unroll
      for (int k = 0; k < 32; ++k) {
        float u = Bs[32 * s + k][tc];
        f32x4 lv = *reinterpret_cast<const f32x4*>(&Lg[(32 * s + k) * 256 + rb]);
        acc[0] = fmaf(-lv[0], u, acc[0]);
        acc[1] = fmaf(-lv[1], u, acc[1]);
        acc[2] = fmaf(-lv[2], u, acc[2]);
        acc[3] = fmaf(-lv[3], u, acc[3]);
      }
      Bs[rb][tc] = acc[0]; Bs[rb + 1][tc] = acc[1];
      Bs[rb + 2][tc] = acc[2]; Bs[rb + 3][tc] = acc[3];
    }
    __syncthreads();
  }
  // backward
#pragma unroll 1
  for (int s = 7; s >= 0; --s) {
    for (int idx = t; idx < 1024; idx += 256) Wl[idx >> 5][idx & 31] = Wbuf[s * 1024 + idx];
    __syncthreads();
    float ga[4] = {0.f, 0.f, 0.f, 0.f};
#pragma unroll
    for (int k = 0; k < 32; ++k) {
      float b = Bs[32 * s + k][tc];
#pragma unroll
      for (int rr = 0; rr < 4; ++rr) ga[rr] = fmaf(Wl[k][rg * 4 + rr], b, ga[rr]);
    }
    __syncthreads();
#pragma unroll
    for (int rr = 0; rr < 4; ++rr) Bs[32 * s + rg * 4 + rr][tc] = ga[rr];
    __syncthreads();
    if (s > 0) {
#pragma unroll 1
      for (int rb = rg * 4; rb < 32 * s; rb += 32) {
        f32x4 acc = {Bs[rb][tc], Bs[rb + 1][tc], Bs[rb + 2][tc], Bs[rb + 3][tc]};
#pragma unroll
        for (int kq = 0; kq < 8; ++kq) {
          f32x4 l0 = *reinterpret_cast<const f32x4*>(&Lg[(rb + 0) * 256 + 32 * s + 4 * kq]);
          f32x4 l1 = *reinterpret_cast<const f32x4*>(&Lg[(rb + 1) * 256 + 32 * s + 4 * kq]);
          f32x4 l2 = *reinterpret_cast<const f32x4*>(&Lg[(rb + 2) * 256 + 32 * s + 4 * kq]);
          f32x4 l3 = *reinterpret_cast<const f32x4*>(&Lg[(rb + 3) * 256 + 32 * s + 4 * kq]);
#pragma unroll
          for (int e = 0; e < 4; ++e) {
            float g = Bs[32 * s + 4 * kq + e][tc];
            acc[0] = fmaf(-l0[e], g, acc[0]);
            acc[1] = fmaf(-l1[e], g, acc[1]);
            acc[2] = fmaf(-l2[e], g, acc[2]);
            acc[3] = fmaf(-l3[e], g, acc[3]);
          }
        }
        Bs[rb][tc] = acc[0]; Bs[rb + 1][tc] = acc[1];
        Bs[rb + 2][tc] = acc[2]; Bs[rb + 3][tc] = acc[3];
      }
    }
    __syncthreads();
  }
#pragma unroll 1
  for (int rr = 0; rr < 32; ++rr) {
    int r = rg * 32 + rr;
    Gout[(size_t)r * DIMH + q] = f2bf(Bs[r][tc]);
  }
}

// ---------------- K6: fused main v7 — 16 rows/wave, 2x wave count ------------------
// Round-12 counters: VALUBusy 25.7 + MfmaUtil 8 = 34% busy, 66% latency-stall at
// OccupancyPercent 23% (grid-capped: 512 blocks = 8 waves/CU). Total waves is set by
// rows/wave; halving to 16 rows/wave doubles waves (4096 -> up to 16/CU). Frag pin
// halves to ~96 regs; launch_bounds(256,3) caps ~170 (NOT 4: round-10 spill cliff).
// Tail = v5 form (best measured), lanes 0..15. B-operand L2 traffic total unchanged.
#define ACCSTR 33
#define ACC_W 2112   // 16 x 33 f32
#define DD_W 2048
#define WT_W 1280    // 16 x 80 B
#define SMEM_MAIN (4 * (ACC_W + DD_W + WT_W))  // 21760 B

__global__ __launch_bounds__(256, 3) void k_main(const float* __restrict__ x,
                                                 const unsigned short* __restrict__ Gin,
                                                 const unsigned short* __restrict__ Gout,
                                                 const float* __restrict__ bv,
                                                 const float* __restrict__ bx,
                                                 float* __restrict__ out) {
  extern __shared__ char smem[];
  int tid = threadIdx.x;
  int wv = tid >> 6, l = tid & 63;
  int lr = l & 15, lq = l >> 4, koff = lq * 8;
  float* accb = (float*)(smem + wv * ACC_W);
  char* ddiag = smem + 4 * ACC_W + wv * DD_W;
  char* wtmp = smem + 4 * ACC_W + 4 * DD_W + wv * WT_W;

  int rowbase = blockIdx.x * 64 + wv * 16;

  // persistent A-operand: chunks 0..7 = x, 8..23 = w; ONE 16-row tile
  bf16x8 frag[24];
  {
    u16x8 zz = {0, 0, 0, 0, 0, 0, 0, 0};
#pragma unroll
    for (int c = 8; c < 24; ++c) frag[c] = __builtin_bit_cast(bf16x8, zz);
  }
#pragma unroll
  for (int kc = 0; kc < 8; ++kc) {
    const float* xr = x + (size_t)(rowbase + lr) * 256 + koff + kc * 32;
    f32x4 a0 = *reinterpret_cast<const f32x4*>(xr);
    f32x4 a1 = *reinterpret_cast<const f32x4*>(xr + 4);
    u16x8 u0;
#pragma unroll
    for (int e = 0; e < 4; ++e) { u0[e] = f2bf(a0[e]); u0[4 + e] = f2bf(a1[e]); }
    frag[kc] = __builtin_bit_cast(bf16x8, u0);
  }

  f32x4 z = {0.f, 0.f, 0.f, 0.f};

#pragma unroll 1
  for (int b = 0; b < 16; ++b) {
    // stage D11 diag block (32x32 bf16, row-major) into per-wave LDS
#pragma unroll
    for (int t = 0; t < 2; ++t) {
      int row = t * 16 + (l >> 2);
      const unsigned short* src =
          Gin + (size_t)(32 * b + row) * DIMH + 256 + 32 * b + (l & 3) * 8;
      u16x8 v = *reinterpret_cast<const u16x8*>(src);
      *reinterpret_cast<u16x8*>(ddiag + t * 1024 + l * 16) = v;
    }

    f32x4 a00 = z, a01 = z;
    const unsigned short* gb0 = Gin + (size_t)(32 * b + lr) * DIMH + koff;
    const unsigned short* gb1 = gb0 + 16 * DIMH;
#pragma unroll
    for (int g = 0; g < 6; ++g) {
      if (g * 4 < 8 + b) {
#pragma unroll
        for (int cc = 0; cc < 4; ++cc) {
          int c = g * 4 + cc;
          bf16x8 bb0 = ld8(gb0 + c * 32);
          bf16x8 bb1 = ld8(gb1 + c * 32);
          a00 = mfma16(frag[c], bb0, a00);
          a01 = mfma16(frag[c], bb1, a01);
        }
      }
    }

    float bv0 = bv[32 * b + lr], bv1 = bv[32 * b + 16 + lr];
#pragma unroll
    for (int r = 0; r < 4; ++r) {
      accb[(lq * 4 + r) * ACCSTR + lr] = a00[r] + bv0;
      accb[(lq * 4 + r) * ACCSTR + 16 + lr] = a01[r] + bv1;
    }

    // serial 32-step tail on lanes 0..15 (lane = sample row); v5 structure
    if (l < 16) {
      const unsigned int* dd = (const unsigned int*)ddiag;
      unsigned int* wrow = (unsigned int*)(wtmp + l * 80);
      float wf[32];
      unsigned int cur = 0;
#pragma unroll
      for (int i = 0; i < 32; ++i) {
        float p0 = 0.f, p1 = 0.f;
        const unsigned int* ddr = dd + i * 16;
#pragma unroll
        for (int j = 0; j < i; ++j) {
          unsigned int pw = ddr[j >> 1];
          float dj = __uint_as_float((j & 1) ? (pw & 0xffff0000u) : (pw << 16));
          if (j & 1) p1 = fmaf(dj, wf[j], p1);
          else       p0 = fmaf(dj, wf[j], p0);
        }
        float s = accb[l * ACCSTR + i] + p0 + p1;
        float e = __builtin_amdgcn_exp2f(s * 2.885390082f);  // e^(2s)
        float w = fmaf(-2.f, __builtin_amdgcn_rcpf(e + 1.f), 1.f);
        wf[i] = w;
        unsigned int hb = (unsigned int)f2bf(w);
        if (i & 1) { cur |= hb << 16; wrow[i >> 1] = cur; }
        else       cur = hb;
      }
    }

    bf16x8 nw0 = ld8((const unsigned short*)(wtmp + lr * 80 + lq * 16));
#pragma unroll
    for (int j = 0; j < 16; ++j) {
      if (b == j) frag[8 + j] = nw0;
    }
  }

  // final GEMM: out = [x | w] @ Gout^T + bx
#pragma unroll 1
  for (int ct = 0; ct < 16; ++ct) {
    f32x4 o0 = z;
    const unsigned short* gg = Gout + (size_t)(ct * 16 + lr) * DIMH + koff;
#pragma unroll
    for (int c = 0; c < 24; ++c) {
      bf16x8 bb = ld8(gg + c * 32);
      o0 = mfma16(frag[c], bb, o0);
    }
    float bxv = bx[ct * 16 + lr];
#pragma unroll
    for (int r = 0; r < 4; ++r)
      out[(size_t)(rowbase + lq * 4 + r) * 256 + ct * 16 + lr] = o0[r] + bxv;
  }
}

extern "C" void kernel_launch(void* const* d_in, const int* in_sizes, int n_in,
                              void* d_out, int out_size, void* d_ws, size_t ws_size,
                              hipStream_t stream) {
  const float* x   = (const float*)d_in[1];
  const float* Pst = (const float*)d_in[2];
  const float* Chi = (const float*)d_in[3];
  const float* X   = (const float*)d_in[4];
  const float* Y1  = (const float*)d_in[5];
  const float* bv  = (const float*)d_in[8];
  const float* bx  = (const float*)d_in[9];
  float* out = (float*)d_out;

  char* ws = (char*)d_ws;
  const size_t OFF_H    = 0;
  const size_t OFF_P    = 2359296;
  const size_t OFF_WB   = 2621440;
  const size_t OFF_XHI  = 2883584;
  const size_t OFF_XLO  = 4063232;
  const size_t OFF_GIN  = 5242880;
  const size_t OFF_GOUT = 6029312;
  if (ws_size < 6422528) return;

  float* H    = (float*)(ws + OFF_H);
  float* P    = (float*)(ws + OFF_P);   // becomes L (lower, col-major) after k_chol
  float* Wbuf = (float*)(ws + OFF_WB);
  unsigned short* Xhi  = (unsigned short*)(ws + OFF_XHI);
  unsigned short* Xlo  = (unsigned short*)(ws + OFF_XLO);
  unsigned short* Gin  = (unsigned short*)(ws + OFF_GIN);
  unsigned short* Gout = (unsigned short*)(ws + OFF_GOUT);

  k_split<<<2304, 256, 0, stream>>>(X, Xhi, Xlo);
  k_syrkP<<<256, 256, 0, stream>>>(Pst, P);
  k_chol<<<1, 256, 0, stream>>>(P, Wbuf);
  k_syrkH<<<144, 256, 0, stream>>>(Xhi, Xlo, H);
  dim3 gg(3, 512);
  k_gin<<<gg, 256, 0, stream>>>(H, Chi, Gin);
  k_gsolve<<<24, 256, 0, stream>>>(P, Wbuf, H, Y1, Chi, Gout);
  k_main<<<1024, 256, SMEM_MAIN, stream>>>(x, Gin, Gout, bv, bx, out);
}

// Round 14
// 911.528 us; speedup vs baseline: 1.1434x; 1.1434x over previous
//
#include <hip/hip_runtime.h>
#include <cstdint>
#include <cstddef>

#define DIMX 256
#define DIMV 512
#define DIMH 768
#define EPSV 0.05f

typedef __bf16 bf16x8 __attribute__((ext_vector_type(8)));
typedef unsigned short u16x8 __attribute__((ext_vector_type(8)));
typedef unsigned int u32x4 __attribute__((ext_vector_type(4)));
typedef float f32x4 __attribute__((ext_vector_type(4)));

__device__ __forceinline__ unsigned short f2bf(float f) {
  unsigned int u = __float_as_uint(f);
  u += 0x7fffu + ((u >> 16) & 1u);
  return (unsigned short)(u >> 16);
}
__device__ __forceinline__ float bf2f(unsigned short b) {
  return __uint_as_float(((unsigned int)b) << 16);
}
__device__ __forceinline__ bf16x8 ld8(const unsigned short* p) {
  u16x8 u = *reinterpret_cast<const u16x8*>(p);
  return __builtin_bit_cast(bf16x8, u);
}
__device__ __forceinline__ f32x4 mfma16(bf16x8 a, bf16x8 b, f32x4 c) {
  return __builtin_amdgcn_mfma_f32_16x16x32_bf16(a, b, c, 0, 0, 0);
}
__device__ __forceinline__ float rdlane(float v, int lane) {
  return __uint_as_float(
      (unsigned int)__builtin_amdgcn_readlane((int)__float_as_uint(v), lane));
}

// ---------------- K0: split X into bf16 hi/lo for split-MFMA SYRK ----------------
__global__ void k_split(const float* __restrict__ X, unsigned short* __restrict__ Xhi,
                        unsigned short* __restrict__ Xlo) {
  int idx = blockIdx.x * 256 + threadIdx.x;
  if (idx < DIMH * DIMH) {
    float f = X[idx];
    unsigned short h = f2bf(f);
    Xhi[idx] = h;
    Xlo[idx] = f2bf(f - bf2f(h));
  }
}

// ---------------- K1: P = 0.5*Pstar@Pstar^T + eps*I (fp32, direct) ----------------
__global__ void k_syrkP(const float* __restrict__ A, float* __restrict__ P) {
  int bi = blockIdx.x >> 4, bj = blockIdx.x & 15;
  int ty = threadIdx.x >> 4, tx = threadIdx.x & 15;
  int i = bi * 16 + ty, j = bj * 16 + tx;
  const f32x4* ra = reinterpret_cast<const f32x4*>(A + (size_t)i * DIMX);
  const f32x4* rb = reinterpret_cast<const f32x4*>(A + (size_t)j * DIMX);
  float s = 0.f;
  for (int k = 0; k < 64; ++k) {
    f32x4 a = ra[k], b = rb[k];
    s = fmaf(a[0], b[0], s); s = fmaf(a[1], b[1], s);
    s = fmaf(a[2], b[2], s); s = fmaf(a[3], b[3], s);
  }
  P[(size_t)i * DIMX + j] = 0.5f * s + (i == j ? EPSV : 0.f);
}

// ---------------- K2: H = X@X^T + eps*I via bf16x2 split MFMA ----------------
__global__ __launch_bounds__(256) void k_syrkH(const unsigned short* __restrict__ Xhi,
                                               const unsigned short* __restrict__ Xlo,
                                               float* __restrict__ H) {
  int bx = blockIdx.x % 12, by = blockIdx.x / 12;
  int i0 = by * 64, j0 = bx * 64;
  int l = threadIdx.x & 63, wv = threadIdx.x >> 6;
  int lr = l & 15, lq = l >> 4;
  int koff = lq * 8;
  int arow = i0 + wv * 16 + lr;
  f32x4 z = {0.f, 0.f, 0.f, 0.f};
  f32x4 acc[4] = {z, z, z, z};
  for (int pass = 0; pass < 3; ++pass) {
    const unsigned short* Xa = (pass == 2) ? Xlo : Xhi;
    const unsigned short* Xb = (pass == 1) ? Xlo : Xhi;
    for (int kc = 0; kc < 24; ++kc) {
      bf16x8 a = ld8(&Xa[(size_t)arow * DIMH + kc * 32 + koff]);
#pragma unroll
      for (int ct = 0; ct < 4; ++ct) {
        bf16x8 b = ld8(&Xb[(size_t)(j0 + ct * 16 + lr) * DIMH + kc * 32 + koff]);
        acc[ct] = mfma16(a, b, acc[ct]);
      }
    }
  }
#pragma unroll
  for (int ct = 0; ct < 4; ++ct)
#pragma unroll
    for (int r = 0; r < 4; ++r) {
      int i = i0 + wv * 16 + lq * 4 + r;
      int j = j0 + ct * 16 + lr;
      H[(size_t)i * DIMH + j] = acc[ct][r] + (i == j ? EPSV : 0.f);
    }
}

// ---------------- K3 v3: blocked Cholesky FULLY IN LDS (packed lower triangle) -----
// Rounds 8-13 accounting: k_chol ~250-300us, dominated by ~32 barrier-phases each with
// global A21/A22 round-trips on a single 4-wave CU. v3: P's lower triangle lives in
// LDS packed (idx(i,j)=i(i+1)/2+j, 131.6KB; round-2 proved >64KB dynamic LDS works).
// One global read (P) at entry, one col-major write (L) at exit; TRSM is in-place
// (row in regs), removing the T-copy phase. Serial readlane core unchanged.
#define CH_SMEM (131584 + 4224)  // packed triangle + Wl[32][33]

__global__ __launch_bounds__(256, 1) void k_chol(float* __restrict__ A,
                                                 float* __restrict__ Wbuf) {
  extern __shared__ float chs[];
  float* Wl = chs + 32896;  // [32][33]
  int t = threadIdx.x;
  int wv = t >> 6, l = t & 63;

  // load P lower triangle (row-major source) into packed LDS
  for (int u = t; u < 32896; u += 256) {
    int i = (int)((sqrtf(8.0f * (float)u + 1.0f) - 1.0f) * 0.5f);
    while ((i + 1) * (i + 2) / 2 <= u) ++i;
    while (i * (i + 1) / 2 > u) --i;
    int j = u - i * (i + 1) / 2;
    chs[u] = A[i * 256 + j];
  }
  __syncthreads();

#pragma unroll 1
  for (int s = 0; s < 8; ++s) {
    int K = 32 * s;
    if (wv == 0) {
      int li = l & 31;
      int rbase = (K + li) * (K + li + 1) / 2 + K;
      float d[32];
#pragma unroll
      for (int j = 0; j < 32; ++j) d[j] = (j <= li) ? chs[rbase + j] : 0.f;
      // pass A: Cholesky of diag block (lane = row, readlane broadcasts)
#pragma unroll
      for (int k = 0; k < 32; ++k) {
        float dkk = rdlane(d[k], k);
        float ip = rsqrtf(dkk);
        d[k] *= ip;
#pragma unroll
        for (int j = k + 1; j < 32; ++j) {
          float ljk = rdlane(d[k], j);
          d[j] = fmaf(-ljk, d[k], d[j]);
        }
      }
      // pass B: W = Ld^{-1} (lane = column)
      float wcol[32];
#pragma unroll
      for (int i = 0; i < 32; ++i) {
        float Lii = rdlane(d[i], i);
        float ipi = 1.0f / Lii;
        float acc = (li == i) ? 1.0f : 0.0f;
#pragma unroll
        for (int k = 0; k < i; ++k) {
          float Lik = rdlane(d[k], i);
          acc = fmaf(-Lik, wcol[k], acc);
        }
        wcol[i] = acc * ipi;
      }
      if (l < 32) {
#pragma unroll
        for (int k = 0; k < 32; ++k) {
          Wl[k * 33 + l] = wcol[k];
          Wbuf[s * 1024 + k * 32 + l] = wcol[k];
        }
        // write factored diag block back (j <= row)
#pragma unroll
        for (int j = 0; j < 32; ++j)
          if (j <= l) chs[rbase + j] = d[j];
      }
    }
    __syncthreads();

    // TRSM in-place: L21[r][:] = A21[r][:] * W^T, one row per thread (row in regs)
    {
      int r = K + 32 + t;
      if (r < 256) {
        int rb = (r * (r + 1) >> 1) + K;
        float arow[32];
#pragma unroll
        for (int k = 0; k < 32; ++k) arow[k] = chs[rb + k];
#pragma unroll
        for (int j = 0; j < 32; ++j) {
          float acc = 0.f;
#pragma unroll
          for (int k = 0; k < 32; ++k) acc = fmaf(arow[k], Wl[j * 33 + k], acc);
          chs[rb + j] = acc;
        }
      }
    }
    __syncthreads();

    // SYRK: A22 -= L21 L21^T on lower 4x4 tiles, all in LDS
    int R32 = 256 - K - 32;
    if (R32 > 0) {
      int T4 = R32 >> 2;
      int ntile = T4 * (T4 + 1) / 2;
      for (int idx = t; idx < ntile; idx += 256) {
        int ti = (int)((sqrtf(8.0f * (float)idx + 1.0f) - 1.0f) * 0.5f);
        while ((ti + 1) * (ti + 2) / 2 <= idx) ++ti;
        while (ti * (ti + 1) / 2 > idx) --ti;
        int tj = idx - ti * (ti + 1) / 2;
        int gi = K + 32 + 4 * ti, gj = K + 32 + 4 * tj;
        int rib[4], rjb[4];
#pragma unroll
        for (int e = 0; e < 4; ++e) {
          rib[e] = ((gi + e) * (gi + e + 1) >> 1);
          rjb[e] = ((gj + e) * (gj + e + 1) >> 1);
        }
        bool diag = (ti == tj);
        float acc[4][4];
#pragma unroll
        for (int e = 0; e < 4; ++e)
#pragma unroll
          for (int jj = 0; jj < 4; ++jj)
            acc[e][jj] = (!diag || e >= jj) ? chs[rib[e] + gj + jj] : 0.f;
#pragma unroll
        for (int k = 0; k < 32; ++k) {
          float av[4], bv[4];
#pragma unroll
          for (int e = 0; e < 4; ++e) {
            av[e] = chs[rib[e] + K + k];
            bv[e] = chs[rjb[e] + K + k];
          }
#pragma unroll
          for (int e = 0; e < 4; ++e)
#pragma unroll
            for (int jj = 0; jj < 4; ++jj)
              acc[e][jj] = fmaf(-av[e], bv[jj], acc[e][jj]);
        }
#pragma unroll
        for (int e = 0; e < 4; ++e)
#pragma unroll
          for (int jj = 0; jj < 4; ++jj)
            if (!diag || e >= jj) chs[rib[e] + gj + jj] = acc[e][jj];
      }
    }
    __syncthreads();
  }

  // store L to A col-major (lower triangle only; upper never read by k_gsolve)
#pragma unroll 1
  for (int j = 0; j < 256; ++j) {
    int i = j + t;
    if (i < 256) A[j * 256 + i] = chs[(i * (i + 1) >> 1) + j];
  }
}

// ---------------- K4: Gin[c][q] = [C1 | D11] as bf16 ----------------
__global__ void k_gin(const float* __restrict__ H, const float* __restrict__ Chi,
                      unsigned short* __restrict__ Gin) {
  int q = blockIdx.x * 256 + threadIdx.x;
  int c = blockIdx.y;
  float rlam = 2.f / H[(size_t)(256 + c) * DIMH + 256 + c];
  float v;
  if (q < 256) {
    v = Chi[(size_t)q * DIMV + c] * rlam;
  } else {
    int j = q - 256;
    v = (j < c) ? -H[(size_t)(256 + c) * DIMH + 256 + j] * rlam : 0.f;
  }
  Gin[(size_t)c * DIMH + q] = f2bf(v);
}

// ---------------- K5: Gout = P^{-1}[Y|M] via BLOCK substitution (GEMM-only) --------
__global__ __launch_bounds__(256, 2) void k_gsolve(const float* __restrict__ Lg,
                                                   const float* __restrict__ Wbuf,
                                                   const float* __restrict__ H,
                                                   const float* __restrict__ Y1,
                                                   const float* __restrict__ Chi,
                                                   unsigned short* __restrict__ Gout) {
  __shared__ float Bs[256][33];
  __shared__ float Wl[32][33];
  int t = threadIdx.x, tc = t & 31, rg = t >> 5;
  int q = blockIdx.x * 32 + tc;
#pragma unroll 1
  for (int rr = 0; rr < 32; ++rr) {
    int r = rg * 32 + rr;
    float v;
    if (q < 256) {
      v = -0.5f * (H[(size_t)r * DIMH + q] + Y1[r * 256 + q] - Y1[q * 256 + r]);
    } else {
      int c = q - 256;
      v = -(H[(size_t)r * DIMH + 256 + c] + Chi[r * 512 + c]);
    }
    Bs[r][tc] = v;
  }
  __syncthreads();
  // forward
#pragma unroll 1
  for (int s = 0; s < 8; ++s) {
    for (int idx = t; idx < 1024; idx += 256) Wl[idx >> 5][idx & 31] = Wbuf[s * 1024 + idx];
    __syncthreads();
    float ua[4] = {0.f, 0.f, 0.f, 0.f};
#pragma unroll
    for (int k = 0; k < 32; ++k) {
      float b = Bs[32 * s + k][tc];
#pragma unroll
      for (int rr = 0; rr < 4; ++rr) ua[rr] = fmaf(Wl[rg * 4 + rr][k], b, ua[rr]);
    }
    __syncthreads();
#pragma unroll
    for (int rr = 0; rr < 4; ++rr) Bs[32 * s + rg * 4 + rr][tc] = ua[rr];
    __syncthreads();
#pragma unroll 1
    for (int rb = 32 * (s + 1) + rg * 4; rb < 256; rb += 32) {
      f32x4 acc = {Bs[rb][tc], Bs[rb + 1][tc], Bs[rb + 2][tc], Bs[rb + 3][tc]};
#pragma unroll
      for (int k = 0; k < 32; ++k) {
        float u = Bs[32 * s + k][tc];
        f32x4 lv = *reinterpret_cast<const f32x4*>(&Lg[(32 * s + k) * 256 + rb]);
        acc[0] = fmaf(-lv[0], u, acc[0]);
        acc[1] = fmaf(-lv[1], u, acc[1]);
        acc[2] = fmaf(-lv[2], u, acc[2]);
        acc[3] = fmaf(-lv[3], u, acc[3]);
      }
      Bs[rb][tc] = acc[0]; Bs[rb + 1][tc] = acc[1];
      Bs[rb + 2][tc] = acc[2]; Bs[rb + 3][tc] = acc[3];
    }
    __syncthreads();
  }
  // backward
#pragma unroll 1
  for (int s = 7; s >= 0; --s) {
    for (int idx = t; idx < 1024; idx += 256) Wl[idx >> 5][idx & 31] = Wbuf[s * 1024 + idx];
    __syncthreads();
    float ga[4] = {0.f, 0.f, 0.f, 0.f};
#pragma unroll
    for (int k = 0; k < 32; ++k) {
      float b = Bs[32 * s + k][tc];
#pragma unroll
      for (int rr = 0; rr < 4; ++rr) ga[rr] = fmaf(Wl[k][rg * 4 + rr], b, ga[rr]);
    }
    __syncthreads();
#pragma unroll
    for (int rr = 0; rr < 4; ++rr) Bs[32 * s + rg * 4 + rr][tc] = ga[rr];
    __syncthreads();
    if (s > 0) {
#pragma unroll 1
      for (int rb = rg * 4; rb < 32 * s; rb += 32) {
        f32x4 acc = {Bs[rb][tc], Bs[rb + 1][tc], Bs[rb + 2][tc], Bs[rb + 3][tc]};
#pragma unroll
        for (int kq = 0; kq < 8; ++kq) {
          f32x4 l0 = *reinterpret_cast<const f32x4*>(&Lg[(rb + 0) * 256 + 32 * s + 4 * kq]);
          f32x4 l1 = *reinterpret_cast<const f32x4*>(&Lg[(rb + 1) * 256 + 32 * s + 4 * kq]);
          f32x4 l2 = *reinterpret_cast<const f32x4*>(&Lg[(rb + 2) * 256 + 32 * s + 4 * kq]);
          f32x4 l3 = *reinterpret_cast<const f32x4*>(&Lg[(rb + 3) * 256 + 32 * s + 4 * kq]);
#pragma unroll
          for (int e = 0; e < 4; ++e) {
            float g = Bs[32 * s + 4 * kq + e][tc];
            acc[0] = fmaf(-l0[e], g, acc[0]);
            acc[1] = fmaf(-l1[e], g, acc[1]);
            acc[2] = fmaf(-l2[e], g, acc[2]);
            acc[3] = fmaf(-l3[e], g, acc[3]);
          }
        }
        Bs[rb][tc] = acc[0]; Bs[rb + 1][tc] = acc[1];
        Bs[rb + 2][tc] = acc[2]; Bs[rb + 3][tc] = acc[3];
      }
    }
    __syncthreads();
  }
#pragma unroll 1
  for (int rr = 0; rr < 32; ++rr) {
    int r = rg * 32 + rr;
    Gout[(size_t)r * DIMH + q] = f2bf(Bs[r][tc]);
  }
}

// ---------------- K6: fused main v5 (round-11 exact — known 311us) ----------------
#define ACCSTR 33
#define ACC_W 4224
#define DD_W 2048
#define WT_W 2560
#define SMEM_MAIN (4 * (ACC_W + DD_W + WT_W))  // 35328 B

__global__ __launch_bounds__(256, 2) void k_main(const float* __restrict__ x,
                                                 const unsigned short* __restrict__ Gin,
                                                 const unsigned short* __restrict__ Gout,
                                                 const float* __restrict__ bv,
                                                 const float* __restrict__ bx,
                                                 float* __restrict__ out) {
  extern __shared__ char smem[];
  int tid = threadIdx.x;
  int wv = tid >> 6, l = tid & 63;
  int lr = l & 15, lq = l >> 4, koff = lq * 8;
  float* accb = (float*)(smem + wv * ACC_W);
  char* ddiag = smem + 4 * ACC_W + wv * DD_W;
  char* wtmp = smem + 4 * ACC_W + 4 * DD_W + wv * WT_W;

  int rowbase = blockIdx.x * 128 + wv * 32;

  bf16x8 frag0[24], frag1[24];
  {
    u16x8 zz = {0, 0, 0, 0, 0, 0, 0, 0};
#pragma unroll
    for (int c = 8; c < 24; ++c) {
      frag0[c] = __builtin_bit_cast(bf16x8, zz);
      frag1[c] = __builtin_bit_cast(bf16x8, zz);
    }
  }
#pragma unroll
  for (int kc = 0; kc < 8; ++kc) {
    const float* xr0 = x + (size_t)(rowbase + lr) * 256 + koff + kc * 32;
    const float* xr1 = x + (size_t)(rowbase + 16 + lr) * 256 + koff + kc * 32;
    f32x4 a0 = *reinterpret_cast<const f32x4*>(xr0);
    f32x4 a1 = *reinterpret_cast<const f32x4*>(xr0 + 4);
    f32x4 b0 = *reinterpret_cast<const f32x4*>(xr1);
    f32x4 b1 = *reinterpret_cast<const f32x4*>(xr1 + 4);
    u16x8 u0, u1;
#pragma unroll
    for (int e = 0; e < 4; ++e) {
      u0[e] = f2bf(a0[e]); u0[4 + e] = f2bf(a1[e]);
      u1[e] = f2bf(b0[e]); u1[4 + e] = f2bf(b1[e]);
    }
    frag0[kc] = __builtin_bit_cast(bf16x8, u0);
    frag1[kc] = __builtin_bit_cast(bf16x8, u1);
  }

  f32x4 z = {0.f, 0.f, 0.f, 0.f};

#pragma unroll 1
  for (int b = 0; b < 16; ++b) {
#pragma unroll
    for (int t = 0; t < 2; ++t) {
      int row = t * 16 + (l >> 2);
      const unsigned short* src =
          Gin + (size_t)(32 * b + row) * DIMH + 256 + 32 * b + (l & 3) * 8;
      u16x8 v = *reinterpret_cast<const u16x8*>(src);
      *reinterpret_cast<u16x8*>(ddiag + t * 1024 + l * 16) = v;
    }

    f32x4 a00 = z, a01 = z, a10 = z, a11 = z;
    const unsigned short* gb0 = Gin + (size_t)(32 * b + lr) * DIMH + koff;
    const unsigned short* gb1 = gb0 + 16 * DIMH;
#pragma unroll
    for (int g = 0; g < 6; ++g) {
      if (g * 4 < 8 + b) {
#pragma unroll
        for (int cc = 0; cc < 4; ++cc) {
          int c = g * 4 + cc;
          bf16x8 bb0 = ld8(gb0 + c * 32);
          bf16x8 bb1 = ld8(gb1 + c * 32);
          a00 = mfma16(frag0[c], bb0, a00);
          a01 = mfma16(frag0[c], bb1, a01);
          a10 = mfma16(frag1[c], bb0, a10);
          a11 = mfma16(frag1[c], bb1, a11);
        }
      }
    }

    float bv0 = bv[32 * b + lr], bv1 = bv[32 * b + 16 + lr];
#pragma unroll
    for (int r = 0; r < 4; ++r) {
      accb[(lq * 4 + r) * ACCSTR + lr] = a00[r] + bv0;
      accb[(lq * 4 + r) * ACCSTR + 16 + lr] = a01[r] + bv1;
      accb[(16 + lq * 4 + r) * ACCSTR + lr] = a10[r] + bv0;
      accb[(16 + lq * 4 + r) * ACCSTR + 16 + lr] = a11[r] + bv1;
    }

    if (l < 32) {
      const unsigned int* dd = (const unsigned int*)ddiag;
      unsigned int* wrow = (unsigned int*)(wtmp + l * 80);
      float wf[32];
      unsigned int cur = 0;
#pragma unroll
      for (int i = 0; i < 32; ++i) {
        float p0 = 0.f, p1 = 0.f;
        const unsigned int* ddr = dd + i * 16;
#pragma unroll
        for (int j = 0; j < i; ++j) {
          unsigned int pw = ddr[j >> 1];
          float dj = __uint_as_float((j & 1) ? (pw & 0xffff0000u) : (pw << 16));
          if (j & 1) p1 = fmaf(dj, wf[j], p1);
          else       p0 = fmaf(dj, wf[j], p0);
        }
        float s = accb[l * ACCSTR + i] + p0 + p1;
        float e = __builtin_amdgcn_exp2f(s * 2.885390082f);
        float w = fmaf(-2.f, __builtin_amdgcn_rcpf(e + 1.f), 1.f);
        wf[i] = w;
        unsigned int hb = (unsigned int)f2bf(w);
        if (i & 1) { cur |= hb << 16; wrow[i >> 1] = cur; }
        else       cur = hb;
      }
    }

    bf16x8 nw0 = ld8((const unsigned short*)(wtmp + lr * 80 + lq * 16));
    bf16x8 nw1 = ld8((const unsigned short*)(wtmp + (16 + lr) * 80 + lq * 16));
#pragma unroll
    for (int j = 0; j < 16; ++j) {
      if (b == j) { frag0[8 + j] = nw0; frag1[8 + j] = nw1; }
    }
  }

#pragma unroll 1
  for (int ct = 0; ct < 16; ++ct) {
    f32x4 o0 = z, o1 = z;
    const unsigned short* gg = Gout + (size_t)(ct * 16 + lr) * DIMH + koff;
#pragma unroll
    for (int c = 0; c < 24; ++c) {
      bf16x8 bb = ld8(gg + c * 32);
      o0 = mfma16(frag0[c], bb, o0);
      o1 = mfma16(frag1[c], bb, o1);
    }
    float bxv = bx[ct * 16 + lr];
#pragma unroll
    for (int r = 0; r < 4; ++r) {
      out[(size_t)(rowbase + lq * 4 + r) * 256 + ct * 16 + lr] = o0[r] + bxv;
      out[(size_t)(rowbase + 16 + lq * 4 + r) * 256 + ct * 16 + lr] = o1[r] + bxv;
    }
  }
}

extern "C" void kernel_launch(void* const* d_in, const int* in_sizes, int n_in,
                              void* d_out, int out_size, void* d_ws, size_t ws_size,
                              hipStream_t stream) {
  const float* x   = (const float*)d_in[1];
  const float* Pst = (const float*)d_in[2];
  const float* Chi = (const float*)d_in[3];
  const float* X   = (const float*)d_in[4];
  const float* Y1  = (const float*)d_in[5];
  const float* bv  = (const float*)d_in[8];
  const float* bx  = (const float*)d_in[9];
  float* out = (float*)d_out;

  char* ws = (char*)d_ws;
  const size_t OFF_H    = 0;
  const size_t OFF_P    = 2359296;
  const size_t OFF_WB   = 2621440;
  const size_t OFF_XHI  = 2883584;
  const size_t OFF_XLO  = 4063232;
  const size_t OFF_GIN  = 5242880;
  const size_t OFF_GOUT = 6029312;
  if (ws_size < 6422528) return;

  float* H    = (float*)(ws + OFF_H);
  float* P    = (float*)(ws + OFF_P);   // becomes L (lower, col-major) after k_chol
  float* Wbuf = (float*)(ws + OFF_WB);
  unsigned short* Xhi  = (unsigned short*)(ws + OFF_XHI);
  unsigned short* Xlo  = (unsigned short*)(ws + OFF_XLO);
  unsigned short* Gin  = (unsigned short*)(ws + OFF_GIN);
  unsigned short* Gout = (unsigned short*)(ws + OFF_GOUT);

  k_split<<<2304, 256, 0, stream>>>(X, Xhi, Xlo);
  k_syrkP<<<256, 256, 0, stream>>>(Pst, P);
  k_chol<<<1, 256, CH_SMEM, stream>>>(P, Wbuf);
  k_syrkH<<<144, 256, 0, stream>>>(Xhi, Xlo, H);
  dim3 gg(3, 512);
  k_gin<<<gg, 256, 0, stream>>>(H, Chi, Gin);
  k_gsolve<<<24, 256, 0, stream>>>(P, Wbuf, H, Y1, Chi, Gout);
  k_main<<<512, 256, SMEM_MAIN, stream>>>(x, Gin, Gout, bv, bx, out);
}

// Round 15
// 716.073 us; speedup vs baseline: 1.4556x; 1.2730x over previous
//
#include <hip/hip_runtime.h>
#include <cstdint>
#include <cstddef>

#define DIMX 256
#define DIMV 512
#define DIMH 768
#define EPSV 0.05f

typedef __bf16 bf16x8 __attribute__((ext_vector_type(8)));
typedef unsigned short u16x8 __attribute__((ext_vector_type(8)));
typedef unsigned int u32x4 __attribute__((ext_vector_type(4)));
typedef float f32x4 __attribute__((ext_vector_type(4)));

__device__ __forceinline__ unsigned short f2bf(float f) {
  unsigned int u = __float_as_uint(f);
  u += 0x7fffu + ((u >> 16) & 1u);
  return (unsigned short)(u >> 16);
}
__device__ __forceinline__ float bf2f(unsigned short b) {
  return __uint_as_float(((unsigned int)b) << 16);
}
__device__ __forceinline__ bf16x8 ld8(const unsigned short* p) {
  u16x8 u = *reinterpret_cast<const u16x8*>(p);
  return __builtin_bit_cast(bf16x8, u);
}
__device__ __forceinline__ f32x4 mfma16(bf16x8 a, bf16x8 b, f32x4 c) {
  return __builtin_amdgcn_mfma_f32_16x16x32_bf16(a, b, c, 0, 0, 0);
}
__device__ __forceinline__ float rdlane(float v, int lane) {
  return __uint_as_float(
      (unsigned int)__builtin_amdgcn_readlane((int)__float_as_uint(v), lane));
}

// ============ K1: syrkP (blocks 0..255)  UNION  split (blocks 256..2559) ============
__global__ __launch_bounds__(256) void k_setup1(const float* __restrict__ X,
                                                unsigned short* __restrict__ Xhi,
                                                unsigned short* __restrict__ Xlo,
                                                const float* __restrict__ Pst,
                                                float* __restrict__ P) {
  int blk = blockIdx.x;
  if (blk < 256) {
    // P = 0.5*Pst@Pst^T + eps*I
    int bi = blk >> 4, bj = blk & 15;
    int ty = threadIdx.x >> 4, tx = threadIdx.x & 15;
    int i = bi * 16 + ty, j = bj * 16 + tx;
    const f32x4* ra = reinterpret_cast<const f32x4*>(Pst + (size_t)i * DIMX);
    const f32x4* rb = reinterpret_cast<const f32x4*>(Pst + (size_t)j * DIMX);
    float s = 0.f;
    for (int k = 0; k < 64; ++k) {
      f32x4 a = ra[k], b = rb[k];
      s = fmaf(a[0], b[0], s); s = fmaf(a[1], b[1], s);
      s = fmaf(a[2], b[2], s); s = fmaf(a[3], b[3], s);
    }
    P[(size_t)i * DIMX + j] = 0.5f * s + (i == j ? EPSV : 0.f);
  } else {
    int idx = (blk - 256) * 256 + threadIdx.x;
    if (idx < DIMH * DIMH) {
      float f = X[idx];
      unsigned short h = f2bf(f);
      Xhi[idx] = h;
      Xlo[idx] = f2bf(f - bf2f(h));
    }
  }
}

// ============ K2: chol (block 0, round-8 body)  UNION  syrkH (blocks 1..144) ========
__global__ __launch_bounds__(256, 1) void k_setup2(float* __restrict__ A,
                                                   float* __restrict__ Wbuf,
                                                   const unsigned short* __restrict__ Xhi,
                                                   const unsigned short* __restrict__ Xlo,
                                                   float* __restrict__ H) {
  __shared__ float Wl[32][33];
  __shared__ float T[32][232];
  if (blockIdx.x == 0) {
    // ---- blocked Cholesky, 256 threads, readlane-serial core (round-8 exact) ----
    int t = threadIdx.x;
    int wv = t >> 6, l = t & 63;
#pragma unroll 1
    for (int s = 0; s < 8; ++s) {
      int K = 32 * s;
      int R32 = 256 - K - 32;
      if (wv == 0) {
        int li = l & 31;
        float d[32];
#pragma unroll
        for (int j = 0; j < 32; ++j) d[j] = A[(K + j) * 256 + K + li];
#pragma unroll
        for (int k = 0; k < 32; ++k) {
          float dkk = rdlane(d[k], k);
          float ip = rsqrtf(dkk);
          d[k] *= ip;
#pragma unroll
          for (int j = k + 1; j < 32; ++j) {
            float ljk = rdlane(d[k], j);
            d[j] = fmaf(-ljk, d[k], d[j]);
          }
        }
        float wcol[32];
#pragma unroll
        for (int i = 0; i < 32; ++i) {
          float Lii = rdlane(d[i], i);
          float ipi = 1.0f / Lii;
          float acc = (li == i) ? 1.0f : 0.0f;
#pragma unroll
          for (int k = 0; k < i; ++k) {
            float Lik = rdlane(d[k], i);
            acc = fmaf(-Lik, wcol[k], acc);
          }
          wcol[i] = acc * ipi;
        }
        if (l < 32) {
#pragma unroll
          for (int k = 0; k < 32; ++k) {
            Wl[k][l] = wcol[k];
            Wbuf[s * 1024 + k * 32 + l] = wcol[k];
          }
        }
      }
      __syncthreads();
      if (R32 > 0) {
        int nrt = R32 >> 2;
        for (int u = t; u < nrt * 8; u += 256) {
          int rt = u >> 3, jg = u & 7;
          int r = K + 32 + rt * 4;
          int j0 = jg * 4;
          f32x4 z4 = {0.f, 0.f, 0.f, 0.f};
          f32x4 acc[4] = {z4, z4, z4, z4};
#pragma unroll
          for (int k = 0; k < 32; ++k) {
            f32x4 av = *reinterpret_cast<const f32x4*>(&A[(K + k) * 256 + r]);
#pragma unroll
            for (int jj = 0; jj < 4; ++jj) {
              float w = Wl[j0 + jj][k];
              acc[jj][0] = fmaf(av[0], w, acc[jj][0]);
              acc[jj][1] = fmaf(av[1], w, acc[jj][1]);
              acc[jj][2] = fmaf(av[2], w, acc[jj][2]);
              acc[jj][3] = fmaf(av[3], w, acc[jj][3]);
            }
          }
#pragma unroll
          for (int jj = 0; jj < 4; ++jj)
            *reinterpret_cast<f32x4*>(&T[j0 + jj][rt * 4]) = acc[jj];
        }
        __syncthreads();
#pragma unroll 1
        for (int j = 0; j < 32; ++j) {
          int rl = t << 2;
          if (rl < R32)
            *reinterpret_cast<f32x4*>(&A[(K + j) * 256 + K + 32 + rl]) =
                *reinterpret_cast<const f32x4*>(&T[j][rl]);
        }
        int T4 = R32 >> 2;
        int ntile = T4 * (T4 + 1) / 2;
        for (int idx = t; idx < ntile; idx += 256) {
          int ti = (int)((sqrtf(8.0f * (float)idx + 1.0f) - 1.0f) * 0.5f);
          while ((ti + 1) * (ti + 2) / 2 <= idx) ++ti;
          while (ti * (ti + 1) / 2 > idx) --ti;
          int tj = idx - ti * (ti + 1) / 2;
          int gi = K + 32 + 4 * ti, gj = K + 32 + 4 * tj;
          f32x4 acc[4];
#pragma unroll
          for (int jj = 0; jj < 4; ++jj)
            acc[jj] = *reinterpret_cast<const f32x4*>(&A[(gj + jj) * 256 + gi]);
#pragma unroll
          for (int k = 0; k < 32; ++k) {
            f32x4 av = *reinterpret_cast<const f32x4*>(&T[k][4 * ti]);
            f32x4 bv = *reinterpret_cast<const f32x4*>(&T[k][4 * tj]);
#pragma unroll
            for (int jj = 0; jj < 4; ++jj) {
              acc[jj][0] = fmaf(-av[0], bv[jj], acc[jj][0]);
              acc[jj][1] = fmaf(-av[1], bv[jj], acc[jj][1]);
              acc[jj][2] = fmaf(-av[2], bv[jj], acc[jj][2]);
              acc[jj][3] = fmaf(-av[3], bv[jj], acc[jj][3]);
            }
          }
#pragma unroll
          for (int jj = 0; jj < 4; ++jj)
            *reinterpret_cast<f32x4*>(&A[(gj + jj) * 256 + gi]) = acc[jj];
        }
      }
      __syncthreads();
    }
  } else {
    // ---- syrkH: H = X@X^T + eps*I via bf16x2 split MFMA ----
    int b2 = blockIdx.x - 1;
    int bx = b2 % 12, by = b2 / 12;
    int i0 = by * 64, j0 = bx * 64;
    int l = threadIdx.x & 63, wv = threadIdx.x >> 6;
    int lr = l & 15, lq = l >> 4;
    int koff = lq * 8;
    int arow = i0 + wv * 16 + lr;
    f32x4 z = {0.f, 0.f, 0.f, 0.f};
    f32x4 acc[4] = {z, z, z, z};
    for (int pass = 0; pass < 3; ++pass) {
      const unsigned short* Xa = (pass == 2) ? Xlo : Xhi;
      const unsigned short* Xb = (pass == 1) ? Xlo : Xhi;
      for (int kc = 0; kc < 24; ++kc) {
        bf16x8 a = ld8(&Xa[(size_t)arow * DIMH + kc * 32 + koff]);
#pragma unroll
        for (int ct = 0; ct < 4; ++ct) {
          bf16x8 b = ld8(&Xb[(size_t)(j0 + ct * 16 + lr) * DIMH + kc * 32 + koff]);
          acc[ct] = mfma16(a, b, acc[ct]);
        }
      }
    }
#pragma unroll
    for (int ct = 0; ct < 4; ++ct)
#pragma unroll
      for (int r = 0; r < 4; ++r) {
        int i = i0 + wv * 16 + lq * 4 + r;
        int j = j0 + ct * 16 + lr;
        H[(size_t)i * DIMH + j] = acc[ct][r] + (i == j ? EPSV : 0.f);
      }
  }
}

// ============ K3: gin (blocks 0..1535)  UNION  gsolve (blocks 1536..1559) ===========
__global__ __launch_bounds__(256, 2) void k_setup3(const float* __restrict__ H,
                                                   const float* __restrict__ Chi,
                                                   unsigned short* __restrict__ Gin,
                                                   const float* __restrict__ Lg,
                                                   const float* __restrict__ Wbuf,
                                                   const float* __restrict__ Y1,
                                                   unsigned short* __restrict__ Gout) {
  __shared__ float Bs[256][33];
  __shared__ float Wl[32][33];
  int blk = blockIdx.x;
  if (blk < 1536) {
    // ---- gin: Gin[c][q] = [C1 | D11] as bf16 ----
    int xb = blk % 3, c = blk / 3;
    int q = xb * 256 + threadIdx.x;
    float rlam = 2.f / H[(size_t)(256 + c) * DIMH + 256 + c];
    float v;
    if (q < 256) {
      v = Chi[(size_t)q * DIMV + c] * rlam;
    } else {
      int j = q - 256;
      v = (j < c) ? -H[(size_t)(256 + c) * DIMH + 256 + j] * rlam : 0.f;
    }
    Gin[(size_t)c * DIMH + q] = f2bf(v);
    return;
  }
  // ---- gsolve: Gout = P^{-1}[Y|M] via block substitution ----
  int bq = blk - 1536;
  int t = threadIdx.x, tc = t & 31, rg = t >> 5;
  int q = bq * 32 + tc;
#pragma unroll 1
  for (int rr = 0; rr < 32; ++rr) {
    int r = rg * 32 + rr;
    float v;
    if (q < 256) {
      v = -0.5f * (H[(size_t)r * DIMH + q] + Y1[r * 256 + q] - Y1[q * 256 + r]);
    } else {
      int c = q - 256;
      v = -(H[(size_t)r * DIMH + 256 + c] + Chi[r * 512 + c]);
    }
    Bs[r][tc] = v;
  }
  __syncthreads();
  // forward
#pragma unroll 1
  for (int s = 0; s < 8; ++s) {
    for (int idx = t; idx < 1024; idx += 256) Wl[idx >> 5][idx & 31] = Wbuf[s * 1024 + idx];
    __syncthreads();
    float ua[4] = {0.f, 0.f, 0.f, 0.f};
#pragma unroll
    for (int k = 0; k < 32; ++k) {
      float b = Bs[32 * s + k][tc];
#pragma unroll
      for (int rr = 0; rr < 4; ++rr) ua[rr] = fmaf(Wl[rg * 4 + rr][k], b, ua[rr]);
    }
    __syncthreads();
#pragma unroll
    for (int rr = 0; rr < 4; ++rr) Bs[32 * s + rg * 4 + rr][tc] = ua[rr];
    __syncthreads();
#pragma unroll 1
    for (int rb = 32 * (s + 1) + rg * 4; rb < 256; rb += 32) {
      f32x4 acc = {Bs[rb][tc], Bs[rb + 1][tc], Bs[rb + 2][tc], Bs[rb + 3][tc]};
#pragma unroll
      for (int k = 0; k < 32; ++k) {
        float u = Bs[32 * s + k][tc];
        f32x4 lv = *reinterpret_cast<const f32x4*>(&Lg[(32 * s + k) * 256 + rb]);
        acc[0] = fmaf(-lv[0], u, acc[0]);
        acc[1] = fmaf(-lv[1], u, acc[1]);
        acc[2] = fmaf(-lv[2], u, acc[2]);
        acc[3] = fmaf(-lv[3], u, acc[3]);
      }
      Bs[rb][tc] = acc[0]; Bs[rb + 1][tc] = acc[1];
      Bs[rb + 2][tc] = acc[2]; Bs[rb + 3][tc] = acc[3];
    }
    __syncthreads();
  }
  // backward
#pragma unroll 1
  for (int s = 7; s >= 0; --s) {
    for (int idx = t; idx < 1024; idx += 256) Wl[idx >> 5][idx & 31] = Wbuf[s * 1024 + idx];
    __syncthreads();
    float ga[4] = {0.f, 0.f, 0.f, 0.f};
#pragma unroll
    for (int k = 0; k < 32; ++k) {
      float b = Bs[32 * s + k][tc];
#pragma unroll
      for (int rr = 0; rr < 4; ++rr) ga[rr] = fmaf(Wl[k][rg * 4 + rr], b, ga[rr]);
    }
    __syncthreads();
#pragma unroll
    for (int rr = 0; rr < 4; ++rr) Bs[32 * s + rg * 4 + rr][tc] = ga[rr];
    __syncthreads();
    if (s > 0) {
#pragma unroll 1
      for (int rb = rg * 4; rb < 32 * s; rb += 32) {
        f32x4 acc = {Bs[rb][tc], Bs[rb + 1][tc], Bs[rb + 2][tc], Bs[rb + 3][tc]};
#pragma unroll
        for (int kq = 0; kq < 8; ++kq) {
          f32x4 l0 = *reinterpret_cast<const f32x4*>(&Lg[(rb + 0) * 256 + 32 * s + 4 * kq]);
          f32x4 l1 = *reinterpret_cast<const f32x4*>(&Lg[(rb + 1) * 256 + 32 * s + 4 * kq]);
          f32x4 l2 = *reinterpret_cast<const f32x4*>(&Lg[(rb + 2) * 256 + 32 * s + 4 * kq]);
          f32x4 l3 = *reinterpret_cast<const f32x4*>(&Lg[(rb + 3) * 256 + 32 * s + 4 * kq]);
#pragma unroll
          for (int e = 0; e < 4; ++e) {
            float g = Bs[32 * s + 4 * kq + e][tc];
            acc[0] = fmaf(-l0[e], g, acc[0]);
            acc[1] = fmaf(-l1[e], g, acc[1]);
            acc[2] = fmaf(-l2[e], g, acc[2]);
            acc[3] = fmaf(-l3[e], g, acc[3]);
          }
        }
        Bs[rb][tc] = acc[0]; Bs[rb + 1][tc] = acc[1];
        Bs[rb + 2][tc] = acc[2]; Bs[rb + 3][tc] = acc[3];
      }
    }
    __syncthreads();
  }
#pragma unroll 1
  for (int rr = 0; rr < 32; ++rr) {
    int r = rg * 32 + rr;
    Gout[(size_t)r * DIMH + q] = f2bf(Bs[r][tc]);
  }
}

// ---------------- K6: fused main v5 (round-11 exact — known 311us) ----------------
#define ACCSTR 33
#define ACC_W 4224
#define DD_W 2048
#define WT_W 2560
#define SMEM_MAIN (4 * (ACC_W + DD_W + WT_W))  // 35328 B

__global__ __launch_bounds__(256, 2) void k_main(const float* __restrict__ x,
                                                 const unsigned short* __restrict__ Gin,
                                                 const unsigned short* __restrict__ Gout,
                                                 const float* __restrict__ bv,
                                                 const float* __restrict__ bx,
                                                 float* __restrict__ out) {
  extern __shared__ char smem[];
  int tid = threadIdx.x;
  int wv = tid >> 6, l = tid & 63;
  int lr = l & 15, lq = l >> 4, koff = lq * 8;
  float* accb = (float*)(smem + wv * ACC_W);
  char* ddiag = smem + 4 * ACC_W + wv * DD_W;
  char* wtmp = smem + 4 * ACC_W + 4 * DD_W + wv * WT_W;

  int rowbase = blockIdx.x * 128 + wv * 32;

  bf16x8 frag0[24], frag1[24];
  {
    u16x8 zz = {0, 0, 0, 0, 0, 0, 0, 0};
#pragma unroll
    for (int c = 8; c < 24; ++c) {
      frag0[c] = __builtin_bit_cast(bf16x8, zz);
      frag1[c] = __builtin_bit_cast(bf16x8, zz);
    }
  }
#pragma unroll
  for (int kc = 0; kc < 8; ++kc) {
    const float* xr0 = x + (size_t)(rowbase + lr) * 256 + koff + kc * 32;
    const float* xr1 = x + (size_t)(rowbase + 16 + lr) * 256 + koff + kc * 32;
    f32x4 a0 = *reinterpret_cast<const f32x4*>(xr0);
    f32x4 a1 = *reinterpret_cast<const f32x4*>(xr0 + 4);
    f32x4 b0 = *reinterpret_cast<const f32x4*>(xr1);
    f32x4 b1 = *reinterpret_cast<const f32x4*>(xr1 + 4);
    u16x8 u0, u1;
#pragma unroll
    for (int e = 0; e < 4; ++e) {
      u0[e] = f2bf(a0[e]); u0[4 + e] = f2bf(a1[e]);
      u1[e] = f2bf(b0[e]); u1[4 + e] = f2bf(b1[e]);
    }
    frag0[kc] = __builtin_bit_cast(bf16x8, u0);
    frag1[kc] = __builtin_bit_cast(bf16x8, u1);
  }

  f32x4 z = {0.f, 0.f, 0.f, 0.f};

#pragma unroll 1
  for (int b = 0; b < 16; ++b) {
#pragma unroll
    for (int t = 0; t < 2; ++t) {
      int row = t * 16 + (l >> 2);
      const unsigned short* src =
          Gin + (size_t)(32 * b + row) * DIMH + 256 + 32 * b + (l & 3) * 8;
      u16x8 v = *reinterpret_cast<const u16x8*>(src);
      *reinterpret_cast<u16x8*>(ddiag + t * 1024 + l * 16) = v;
    }

    f32x4 a00 = z, a01 = z, a10 = z, a11 = z;
    const unsigned short* gb0 = Gin + (size_t)(32 * b + lr) * DIMH + koff;
    const unsigned short* gb1 = gb0 + 16 * DIMH;
#pragma unroll
    for (int g = 0; g < 6; ++g) {
      if (g * 4 < 8 + b) {
#pragma unroll
        for (int cc = 0; cc < 4; ++cc) {
          int c = g * 4 + cc;
          bf16x8 bb0 = ld8(gb0 + c * 32);
          bf16x8 bb1 = ld8(gb1 + c * 32);
          a00 = mfma16(frag0[c], bb0, a00);
          a01 = mfma16(frag0[c], bb1, a01);
          a10 = mfma16(frag1[c], bb0, a10);
          a11 = mfma16(frag1[c], bb1, a11);
        }
      }
    }

    float bv0 = bv[32 * b + lr], bv1 = bv[32 * b + 16 + lr];
#pragma unroll
    for (int r = 0; r < 4; ++r) {
      accb[(lq * 4 + r) * ACCSTR + lr] = a00[r] + bv0;
      accb[(lq * 4 + r) * ACCSTR + 16 + lr] = a01[r] + bv1;
      accb[(16 + lq * 4 + r) * ACCSTR + lr] = a10[r] + bv0;
      accb[(16 + lq * 4 + r) * ACCSTR + 16 + lr] = a11[r] + bv1;
    }

    if (l < 32) {
      const unsigned int* dd = (const unsigned int*)ddiag;
      unsigned int* wrow = (unsigned int*)(wtmp + l * 80);
      float wf[32];
      unsigned int cur = 0;
#pragma unroll
      for (int i = 0; i < 32; ++i) {
        float p0 = 0.f, p1 = 0.f;
        const unsigned int* ddr = dd + i * 16;
#pragma unroll
        for (int j = 0; j < i; ++j) {
          unsigned int pw = ddr[j >> 1];
          float dj = __uint_as_float((j & 1) ? (pw & 0xffff0000u) : (pw << 16));
          if (j & 1) p1 = fmaf(dj, wf[j], p1);
          else       p0 = fmaf(dj, wf[j], p0);
        }
        float s = accb[l * ACCSTR + i] + p0 + p1;
        float e = __builtin_amdgcn_exp2f(s * 2.885390082f);
        float w = fmaf(-2.f, __builtin_amdgcn_rcpf(e + 1.f), 1.f);
        wf[i] = w;
        unsigned int hb = (unsigned int)f2bf(w);
        if (i & 1) { cur |= hb << 16; wrow[i >> 1] = cur; }
        else       cur = hb;
      }
    }

    bf16x8 nw0 = ld8((const unsigned short*)(wtmp + lr * 80 + lq * 16));
    bf16x8 nw1 = ld8((const unsigned short*)(wtmp + (16 + lr) * 80 + lq * 16));
#pragma unroll
    for (int j = 0; j < 16; ++j) {
      if (b == j) { frag0[8 + j] = nw0; frag1[8 + j] = nw1; }
    }
  }

#pragma unroll 1
  for (int ct = 0; ct < 16; ++ct) {
    f32x4 o0 = z, o1 = z;
    const unsigned short* gg = Gout + (size_t)(ct * 16 + lr) * DIMH + koff;
#pragma unroll
    for (int c = 0; c < 24; ++c) {
      bf16x8 bb = ld8(gg + c * 32);
      o0 = mfma16(frag0[c], bb, o0);
      o1 = mfma16(frag1[c], bb, o1);
    }
    float bxv = bx[ct * 16 + lr];
#pragma unroll
    for (int r = 0; r < 4; ++r) {
      out[(size_t)(rowbase + lq * 4 + r) * 256 + ct * 16 + lr] = o0[r] + bxv;
      out[(size_t)(rowbase + 16 + lq * 4 + r) * 256 + ct * 16 + lr] = o1[r] + bxv;
    }
  }
}

extern "C" void kernel_launch(void* const* d_in, const int* in_sizes, int n_in,
                              void* d_out, int out_size, void* d_ws, size_t ws_size,
                              hipStream_t stream) {
  const float* x   = (const float*)d_in[1];
  const float* Pst = (const float*)d_in[2];
  const float* Chi = (const float*)d_in[3];
  const float* X   = (const float*)d_in[4];
  const float* Y1  = (const float*)d_in[5];
  const float* bv  = (const float*)d_in[8];
  const float* bx  = (const float*)d_in[9];
  float* out = (float*)d_out;

  char* ws = (char*)d_ws;
  const size_t OFF_H    = 0;
  const size_t OFF_P    = 2359296;
  const size_t OFF_WB   = 2621440;
  const size_t OFF_XHI  = 2883584;
  const size_t OFF_XLO  = 4063232;
  const size_t OFF_GIN  = 5242880;
  const size_t OFF_GOUT = 6029312;
  if (ws_size < 6422528) return;

  float* H    = (float*)(ws + OFF_H);
  float* P    = (float*)(ws + OFF_P);   // becomes L (lower, col-major) after k_setup2
  float* Wbuf = (float*)(ws + OFF_WB);
  unsigned short* Xhi  = (unsigned short*)(ws + OFF_XHI);
  unsigned short* Xlo  = (unsigned short*)(ws + OFF_XLO);
  unsigned short* Gin  = (unsigned short*)(ws + OFF_GIN);
  unsigned short* Gout = (unsigned short*)(ws + OFF_GOUT);

  k_setup1<<<2560, 256, 0, stream>>>(X, Xhi, Xlo, Pst, P);
  k_setup2<<<145, 256, 0, stream>>>(P, Wbuf, Xhi, Xlo, H);
  k_setup3<<<1560, 256, 0, stream>>>(H, Chi, Gin, P, Wbuf, Y1, Gout);
  k_main<<<512, 256, SMEM_MAIN, stream>>>(x, Gin, Gout, bv, bx, out);
}

// Round 16
// 606.060 us; speedup vs baseline: 1.7198x; 1.1815x over previous
//
#include <hip/hip_runtime.h>
#include <cstdint>
#include <cstddef>

#define DIMX 256
#define DIMV 512
#define DIMH 768
#define EPSV 0.05f

typedef __bf16 bf16x8 __attribute__((ext_vector_type(8)));
typedef unsigned short u16x8 __attribute__((ext_vector_type(8)));
typedef unsigned int u32x4 __attribute__((ext_vector_type(4)));
typedef float f32x4 __attribute__((ext_vector_type(4)));

__device__ __forceinline__ unsigned short f2bf(float f) {
  unsigned int u = __float_as_uint(f);
  u += 0x7fffu + ((u >> 16) & 1u);
  return (unsigned short)(u >> 16);
}
__device__ __forceinline__ float bf2f(unsigned short b) {
  return __uint_as_float(((unsigned int)b) << 16);
}
__device__ __forceinline__ bf16x8 ld8(const unsigned short* p) {
  u16x8 u = *reinterpret_cast<const u16x8*>(p);
  return __builtin_bit_cast(bf16x8, u);
}
__device__ __forceinline__ f32x4 mfma16(bf16x8 a, bf16x8 b, f32x4 c) {
  return __builtin_amdgcn_mfma_f32_16x16x32_bf16(a, b, c, 0, 0, 0);
}
__device__ __forceinline__ float rdlane(float v, int lane) {
  return __uint_as_float(
      (unsigned int)__builtin_amdgcn_readlane((int)__float_as_uint(v), lane));
}

// ============ K1: syrkP (blocks 0..255)  UNION  split (blocks 256..2559) ============
__global__ __launch_bounds__(256) void k_setup1(const float* __restrict__ X,
                                                unsigned short* __restrict__ Xhi,
                                                unsigned short* __restrict__ Xlo,
                                                const float* __restrict__ Pst,
                                                float* __restrict__ P) {
  int blk = blockIdx.x;
  if (blk < 256) {
    int bi = blk >> 4, bj = blk & 15;
    int ty = threadIdx.x >> 4, tx = threadIdx.x & 15;
    int i = bi * 16 + ty, j = bj * 16 + tx;
    const f32x4* ra = reinterpret_cast<const f32x4*>(Pst + (size_t)i * DIMX);
    const f32x4* rb = reinterpret_cast<const f32x4*>(Pst + (size_t)j * DIMX);
    float s = 0.f;
    for (int k = 0; k < 64; ++k) {
      f32x4 a = ra[k], b = rb[k];
      s = fmaf(a[0], b[0], s); s = fmaf(a[1], b[1], s);
      s = fmaf(a[2], b[2], s); s = fmaf(a[3], b[3], s);
    }
    P[(size_t)i * DIMX + j] = 0.5f * s + (i == j ? EPSV : 0.f);
  } else {
    int idx = (blk - 256) * 256 + threadIdx.x;
    if (idx < DIMH * DIMH) {
      float f = X[idx];
      unsigned short h = f2bf(f);
      Xhi[idx] = h;
      Xlo[idx] = f2bf(f - bf2f(h));
    }
  }
}

// ============ K2: chol + Linv (block 0)  UNION  syrkH (blocks 1..144) ===============
// Block 0: round-8 blocked Cholesky (readlane-serial core), then Linv = L^{-1}
// blockwise (7 levels, LDS-staged panels). Li (dense lower, row-major 256x256)
// borrows the Gout ws region (dead until k_gout overwrites). Replaces gsolve's
// 16-step barrier-latency chain with parallel GEMMs downstream.
__global__ __launch_bounds__(256, 1) void k_setup2(float* __restrict__ A,
                                                   float* __restrict__ Li,
                                                   const unsigned short* __restrict__ Xhi,
                                                   const unsigned short* __restrict__ Xlo,
                                                   float* __restrict__ H) {
  __shared__ float Wl[32][33];
  __shared__ float T[32][232];    // TRSM staging; later Linv T-scratch (7424 f32)
  __shared__ float Lp2[224][33];  // Linv: L row-panel staged transposed
  if (blockIdx.x == 0) {
    int t = threadIdx.x;
    int wv = t >> 6, l = t & 63;
#pragma unroll 1
    for (int s = 0; s < 8; ++s) {
      int K = 32 * s;
      int R32 = 256 - K - 32;
      if (wv == 0) {
        int li = l & 31;
        float d[32];
#pragma unroll
        for (int j = 0; j < 32; ++j) d[j] = A[(K + j) * 256 + K + li];
#pragma unroll
        for (int k = 0; k < 32; ++k) {
          float dkk = rdlane(d[k], k);
          float ip = rsqrtf(dkk);
          d[k] *= ip;
#pragma unroll
          for (int j = k + 1; j < 32; ++j) {
            float ljk = rdlane(d[k], j);
            d[j] = fmaf(-ljk, d[k], d[j]);
          }
        }
        float wcol[32];
#pragma unroll
        for (int i = 0; i < 32; ++i) {
          float Lii = rdlane(d[i], i);
          float ipi = 1.0f / Lii;
          float acc = (li == i) ? 1.0f : 0.0f;
#pragma unroll
          for (int k = 0; k < i; ++k) {
            float Lik = rdlane(d[k], i);
            acc = fmaf(-Lik, wcol[k], acc);
          }
          wcol[i] = acc * ipi;
        }
        if (l < 32) {
#pragma unroll
          for (int k = 0; k < 32; ++k) {
            Wl[k][l] = wcol[k];
            Li[(32 * s + k) * 256 + 32 * s + l] = wcol[k];  // Linv diag = W_s
          }
        }
      }
      __syncthreads();
      if (R32 > 0) {
        int nrt = R32 >> 2;
        for (int u = t; u < nrt * 8; u += 256) {
          int rt = u >> 3, jg = u & 7;
          int r = K + 32 + rt * 4;
          int j0 = jg * 4;
          f32x4 z4 = {0.f, 0.f, 0.f, 0.f};
          f32x4 acc[4] = {z4, z4, z4, z4};
#pragma unroll
          for (int k = 0; k < 32; ++k) {
            f32x4 av = *reinterpret_cast<const f32x4*>(&A[(K + k) * 256 + r]);
#pragma unroll
            for (int jj = 0; jj < 4; ++jj) {
              float w = Wl[j0 + jj][k];
              acc[jj][0] = fmaf(av[0], w, acc[jj][0]);
              acc[jj][1] = fmaf(av[1], w, acc[jj][1]);
              acc[jj][2] = fmaf(av[2], w, acc[jj][2]);
              acc[jj][3] = fmaf(av[3], w, acc[jj][3]);
            }
          }
#pragma unroll
          for (int jj = 0; jj < 4; ++jj)
            *reinterpret_cast<f32x4*>(&T[j0 + jj][rt * 4]) = acc[jj];
        }
        __syncthreads();
#pragma unroll 1
        for (int j = 0; j < 32; ++j) {
          int rl = t << 2;
          if (rl < R32)
            *reinterpret_cast<f32x4*>(&A[(K + j) * 256 + K + 32 + rl]) =
                *reinterpret_cast<const f32x4*>(&T[j][rl]);
        }
        int T4 = R32 >> 2;
        int ntile = T4 * (T4 + 1) / 2;
        for (int idx = t; idx < ntile; idx += 256) {
          int ti = (int)((sqrtf(8.0f * (float)idx + 1.0f) - 1.0f) * 0.5f);
          while ((ti + 1) * (ti + 2) / 2 <= idx) ++ti;
          while (ti * (ti + 1) / 2 > idx) --ti;
          int tj = idx - ti * (ti + 1) / 2;
          int gi = K + 32 + 4 * ti, gj = K + 32 + 4 * tj;
          f32x4 acc[4];
#pragma unroll
          for (int jj = 0; jj < 4; ++jj)
            acc[jj] = *reinterpret_cast<const f32x4*>(&A[(gj + jj) * 256 + gi]);
#pragma unroll
          for (int k = 0; k < 32; ++k) {
            f32x4 av = *reinterpret_cast<const f32x4*>(&T[k][4 * ti]);
            f32x4 bv = *reinterpret_cast<const f32x4*>(&T[k][4 * tj]);
#pragma unroll
            for (int jj = 0; jj < 4; ++jj) {
              acc[jj][0] = fmaf(-av[0], bv[jj], acc[jj][0]);
              acc[jj][1] = fmaf(-av[1], bv[jj], acc[jj][1]);
              acc[jj][2] = fmaf(-av[2], bv[jj], acc[jj][2]);
              acc[jj][3] = fmaf(-av[3], bv[jj], acc[jj][3]);
            }
          }
#pragma unroll
          for (int jj = 0; jj < 4; ++jj)
            *reinterpret_cast<f32x4*>(&A[(gj + jj) * 256 + gi]) = acc[jj];
        }
      }
      __syncthreads();
    }

    // ---- Linv levels: for i=1..7, Linv_ij = -W_i * (sum_{k=j}^{i-1} L_ik Linv_kj) ----
    float* Tb = &T[0][0];
#pragma unroll 1
    for (int i = 1; i < 8; ++i) {
      // stage Lp2[cc][r] = L[32i+r][cc] for cc < 32i; stage Wl = W_i from Li diag
      for (int idx = t; idx < 32 * 32 * i; idx += 256) {
        int r = idx & 31, cc = idx >> 5;
        Lp2[cc][r] = A[cc * 256 + 32 * i + r];
      }
      for (int idx = t; idx < 1024; idx += 256) {
        int r = idx >> 5, kk = idx & 31;
        Wl[r][kk] = Li[(32 * i + r) * 256 + 32 * i + kk];
      }
      __syncthreads();
      // phase 1: T_j = sum_k L_ik Linv_kj  (4x4 tiles)
      int nt1 = i * 64;
      for (int u = t; u < nt1; u += 256) {
        int j = u >> 6, v = u & 63;
        int r0 = (v >> 3) * 4, c0 = (v & 7) * 4;
        f32x4 z4 = {0.f, 0.f, 0.f, 0.f};
        f32x4 acc[4] = {z4, z4, z4, z4};
        for (int k = j; k < i; ++k) {
#pragma unroll
          for (int kk = 0; kk < 32; ++kk) {
            f32x4 lv = *reinterpret_cast<const f32x4*>(
                &Li[(32 * k + kk) * 256 + 32 * j + c0]);
#pragma unroll
            for (int e = 0; e < 4; ++e) {
              float lpe = Lp2[32 * k + kk][r0 + e];
              acc[e][0] = fmaf(lpe, lv[0], acc[e][0]);
              acc[e][1] = fmaf(lpe, lv[1], acc[e][1]);
              acc[e][2] = fmaf(lpe, lv[2], acc[e][2]);
              acc[e][3] = fmaf(lpe, lv[3], acc[e][3]);
            }
          }
        }
#pragma unroll
        for (int e = 0; e < 4; ++e)
          *reinterpret_cast<f32x4*>(&Tb[j * 1024 + (r0 + e) * 32 + c0]) = acc[e];
      }
      __syncthreads();
      // phase 2: Linv_ij = -W_i T_j
      for (int u = t; u < nt1; u += 256) {
        int j = u >> 6, v = u & 63;
        int r0 = (v >> 3) * 4, c0 = (v & 7) * 4;
        f32x4 z4 = {0.f, 0.f, 0.f, 0.f};
        f32x4 acc[4] = {z4, z4, z4, z4};
#pragma unroll
        for (int kk = 0; kk < 32; ++kk) {
          f32x4 tv = *reinterpret_cast<const f32x4*>(&Tb[j * 1024 + kk * 32 + c0]);
#pragma unroll
          for (int e = 0; e < 4; ++e) {
            float w = Wl[r0 + e][kk];
            acc[e][0] = fmaf(-w, tv[0], acc[e][0]);
            acc[e][1] = fmaf(-w, tv[1], acc[e][1]);
            acc[e][2] = fmaf(-w, tv[2], acc[e][2]);
            acc[e][3] = fmaf(-w, tv[3], acc[e][3]);
          }
        }
#pragma unroll
        for (int e = 0; e < 4; ++e)
          *reinterpret_cast<f32x4*>(&Li[(32 * i + r0 + e) * 256 + 32 * j + c0]) =
              acc[e];
      }
      __syncthreads();
    }
  } else {
    // ---- syrkH: H = X@X^T + eps*I via bf16x2 split MFMA ----
    int b2 = blockIdx.x - 1;
    int bx = b2 % 12, by = b2 / 12;
    int i0 = by * 64, j0 = bx * 64;
    int l = threadIdx.x & 63, wv = threadIdx.x >> 6;
    int lr = l & 15, lq = l >> 4;
    int koff = lq * 8;
    int arow = i0 + wv * 16 + lr;
    f32x4 z = {0.f, 0.f, 0.f, 0.f};
    f32x4 acc[4] = {z, z, z, z};
    for (int pass = 0; pass < 3; ++pass) {
      const unsigned short* Xa = (pass == 2) ? Xlo : Xhi;
      const unsigned short* Xb = (pass == 1) ? Xlo : Xhi;
      for (int kc = 0; kc < 24; ++kc) {
        bf16x8 a = ld8(&Xa[(size_t)arow * DIMH + kc * 32 + koff]);
#pragma unroll
        for (int ct = 0; ct < 4; ++ct) {
          bf16x8 b = ld8(&Xb[(size_t)(j0 + ct * 16 + lr) * DIMH + kc * 32 + koff]);
          acc[ct] = mfma16(a, b, acc[ct]);
        }
      }
    }
#pragma unroll
    for (int ct = 0; ct < 4; ++ct)
#pragma unroll
      for (int r = 0; r < 4; ++r) {
        int i = i0 + wv * 16 + lq * 4 + r;
        int j = j0 + ct * 16 + lr;
        H[(size_t)i * DIMH + j] = acc[ct][r] + (i == j ? EPSV : 0.f);
      }
  }
}

// ============ K3: pinv (blocks 0..35)  UNION  gin (blocks 36..1571) =================
// pinv: Pinv = Linv^T Linv (block-pair (bi>=bj); k-blocks >= bi). Pinv overwrites L
// at OFF_P (dead). gin unchanged.
__global__ __launch_bounds__(256, 2) void k_setup3(const float* __restrict__ H,
                                                   const float* __restrict__ Chi,
                                                   unsigned short* __restrict__ Gin,
                                                   const float* __restrict__ Li,
                                                   float* __restrict__ Pinv) {
  int blk = blockIdx.x;
  int t = threadIdx.x;
  if (blk < 36) {
    int bi = (int)((sqrtf(8.0f * (float)blk + 1.0f) - 1.0f) * 0.5f);
    while ((bi + 1) * (bi + 2) / 2 <= blk) ++bi;
    while (bi * (bi + 1) / 2 > blk) --bi;
    int bj = blk - bi * (bi + 1) / 2;
    int r = t >> 3, c0 = (t & 7) * 4;
    f32x4 acc = {0.f, 0.f, 0.f, 0.f};
    for (int kb = bi; kb < 8; ++kb) {
#pragma unroll
      for (int kk = 0; kk < 32; ++kk) {
        float a = Li[(32 * kb + kk) * 256 + 32 * bi + r];
        f32x4 b = *reinterpret_cast<const f32x4*>(
            &Li[(32 * kb + kk) * 256 + 32 * bj + c0]);
        acc[0] = fmaf(a, b[0], acc[0]);
        acc[1] = fmaf(a, b[1], acc[1]);
        acc[2] = fmaf(a, b[2], acc[2]);
        acc[3] = fmaf(a, b[3], acc[3]);
      }
    }
    *reinterpret_cast<f32x4*>(&Pinv[(32 * bi + r) * 256 + 32 * bj + c0]) = acc;
    if (bi != bj) {
#pragma unroll
      for (int e = 0; e < 4; ++e)
        Pinv[(32 * bj + c0 + e) * 256 + 32 * bi + r] = acc[e];
    }
    return;
  }
  int b2 = blk - 36;
  int xb = b2 % 3, c = b2 / 3;
  int q = xb * 256 + t;
  float rlam = 2.f / H[(size_t)(256 + c) * DIMH + 256 + c];
  float v;
  if (q < 256) {
    v = Chi[(size_t)q * DIMV + c] * rlam;
  } else {
    int j = q - 256;
    v = (j < c) ? -H[(size_t)(256 + c) * DIMH + 256 + j] * rlam : 0.f;
  }
  Gin[(size_t)c * DIMH + q] = f2bf(v);
}

// ============ K4: Gout = Pinv @ [Y | M] (round-0 proven kernel) =====================
__global__ __launch_bounds__(256) void k_gout(const float* __restrict__ Pinv,
                                              const float* __restrict__ H,
                                              const float* __restrict__ Y1,
                                              const float* __restrict__ Chi,
                                              unsigned short* __restrict__ Gout) {
  __shared__ float Ps[32][33], Bs[32][33];
  int q0 = blockIdx.x * 32, i0 = blockIdx.y * 32;
  int t = threadIdx.x;
  int tx = t & 31, ty = t >> 5;
  int lrr = t >> 3, lc4 = (t & 7) * 4;
  float acc[4] = {0.f, 0.f, 0.f, 0.f};
  for (int kc = 0; kc < 8; ++kc) {
    int k0 = kc * 32;
    f32x4 pv = *reinterpret_cast<const f32x4*>(&Pinv[(size_t)(i0 + lrr) * 256 + k0 + lc4]);
    Ps[lrr][lc4 + 0] = pv[0]; Ps[lrr][lc4 + 1] = pv[1];
    Ps[lrr][lc4 + 2] = pv[2]; Ps[lrr][lc4 + 3] = pv[3];
    int k = k0 + lrr;
#pragma unroll
    for (int e = 0; e < 4; ++e) {
      int q = q0 + lc4 + e;
      float v;
      if (q < 256) {
        v = -0.5f * (H[(size_t)k * DIMH + q] + Y1[(size_t)k * 256 + q] - Y1[(size_t)q * 256 + k]);
      } else {
        int c = q - 256;
        v = -(H[(size_t)k * DIMH + 256 + c] + Chi[(size_t)k * DIMV + c]);
      }
      Bs[lrr][lc4 + e] = v;
    }
    __syncthreads();
#pragma unroll
    for (int kk = 0; kk < 32; ++kk) {
      float bb = Bs[kk][tx];
#pragma unroll
      for (int rr = 0; rr < 4; ++rr) acc[rr] = fmaf(Ps[4 * ty + rr][kk], bb, acc[rr]);
    }
    __syncthreads();
  }
#pragma unroll
  for (int rr = 0; rr < 4; ++rr)
    Gout[(size_t)(i0 + 4 * ty + rr) * DIMH + q0 + tx] = f2bf(acc[rr]);
}

// ---------------- K6: fused main v5 (round-11 exact — known 311us) ----------------
#define ACCSTR 33
#define ACC_W 4224
#define DD_W 2048
#define WT_W 2560
#define SMEM_MAIN (4 * (ACC_W + DD_W + WT_W))  // 35328 B

__global__ __launch_bounds__(256, 2) void k_main(const float* __restrict__ x,
                                                 const unsigned short* __restrict__ Gin,
                                                 const unsigned short* __restrict__ Gout,
                                                 const float* __restrict__ bv,
                                                 const float* __restrict__ bx,
                                                 float* __restrict__ out) {
  extern __shared__ char smem[];
  int tid = threadIdx.x;
  int wv = tid >> 6, l = tid & 63;
  int lr = l & 15, lq = l >> 4, koff = lq * 8;
  float* accb = (float*)(smem + wv * ACC_W);
  char* ddiag = smem + 4 * ACC_W + wv * DD_W;
  char* wtmp = smem + 4 * ACC_W + 4 * DD_W + wv * WT_W;

  int rowbase = blockIdx.x * 128 + wv * 32;

  bf16x8 frag0[24], frag1[24];
  {
    u16x8 zz = {0, 0, 0, 0, 0, 0, 0, 0};
#pragma unroll
    for (int c = 8; c < 24; ++c) {
      frag0[c] = __builtin_bit_cast(bf16x8, zz);
      frag1[c] = __builtin_bit_cast(bf16x8, zz);
    }
  }
#pragma unroll
  for (int kc = 0; kc < 8; ++kc) {
    const float* xr0 = x + (size_t)(rowbase + lr) * 256 + koff + kc * 32;
    const float* xr1 = x + (size_t)(rowbase + 16 + lr) * 256 + koff + kc * 32;
    f32x4 a0 = *reinterpret_cast<const f32x4*>(xr0);
    f32x4 a1 = *reinterpret_cast<const f32x4*>(xr0 + 4);
    f32x4 b0 = *reinterpret_cast<const f32x4*>(xr1);
    f32x4 b1 = *reinterpret_cast<const f32x4*>(xr1 + 4);
    u16x8 u0, u1;
#pragma unroll
    for (int e = 0; e < 4; ++e) {
      u0[e] = f2bf(a0[e]); u0[4 + e] = f2bf(a1[e]);
      u1[e] = f2bf(b0[e]); u1[4 + e] = f2bf(b1[e]);
    }
    frag0[kc] = __builtin_bit_cast(bf16x8, u0);
    frag1[kc] = __builtin_bit_cast(bf16x8, u1);
  }

  f32x4 z = {0.f, 0.f, 0.f, 0.f};

#pragma unroll 1
  for (int b = 0; b < 16; ++b) {
#pragma unroll
    for (int t = 0; t < 2; ++t) {
      int row = t * 16 + (l >> 2);
      const unsigned short* src =
          Gin + (size_t)(32 * b + row) * DIMH + 256 + 32 * b + (l & 3) * 8;
      u16x8 v = *reinterpret_cast<const u16x8*>(src);
      *reinterpret_cast<u16x8*>(ddiag + t * 1024 + l * 16) = v;
    }

    f32x4 a00 = z, a01 = z, a10 = z, a11 = z;
    const unsigned short* gb0 = Gin + (size_t)(32 * b + lr) * DIMH + koff;
    const unsigned short* gb1 = gb0 + 16 * DIMH;
#pragma unroll
    for (int g = 0; g < 6; ++g) {
      if (g * 4 < 8 + b) {
#pragma unroll
        for (int cc = 0; cc < 4; ++cc) {
          int c = g * 4 + cc;
          bf16x8 bb0 = ld8(gb0 + c * 32);
          bf16x8 bb1 = ld8(gb1 + c * 32);
          a00 = mfma16(frag0[c], bb0, a00);
          a01 = mfma16(frag0[c], bb1, a01);
          a10 = mfma16(frag1[c], bb0, a10);
          a11 = mfma16(frag1[c], bb1, a11);
        }
      }
    }

    float bv0 = bv[32 * b + lr], bv1 = bv[32 * b + 16 + lr];
#pragma unroll
    for (int r = 0; r < 4; ++r) {
      accb[(lq * 4 + r) * ACCSTR + lr] = a00[r] + bv0;
      accb[(lq * 4 + r) * ACCSTR + 16 + lr] = a01[r] + bv1;
      accb[(16 + lq * 4 + r) * ACCSTR + lr] = a10[r] + bv0;
      accb[(16 + lq * 4 + r) * ACCSTR + 16 + lr] = a11[r] + bv1;
    }

    if (l < 32) {
      const unsigned int* dd = (const unsigned int*)ddiag;
      unsigned int* wrow = (unsigned int*)(wtmp + l * 80);
      float wf[32];
      unsigned int cur = 0;
#pragma unroll
      for (int i = 0; i < 32; ++i) {
        float p0 = 0.f, p1 = 0.f;
        const unsigned int* ddr = dd + i * 16;
#pragma unroll
        for (int j = 0; j < i; ++j) {
          unsigned int pw = ddr[j >> 1];
          float dj = __uint_as_float((j & 1) ? (pw & 0xffff0000u) : (pw << 16));
          if (j & 1) p1 = fmaf(dj, wf[j], p1);
          else       p0 = fmaf(dj, wf[j], p0);
        }
        float s = accb[l * ACCSTR + i] + p0 + p1;
        float e = __builtin_amdgcn_exp2f(s * 2.885390082f);
        float w = fmaf(-2.f, __builtin_amdgcn_rcpf(e + 1.f), 1.f);
        wf[i] = w;
        unsigned int hb = (unsigned int)f2bf(w);
        if (i & 1) { cur |= hb << 16; wrow[i >> 1] = cur; }
        else       cur = hb;
      }
    }

    bf16x8 nw0 = ld8((const unsigned short*)(wtmp + lr * 80 + lq * 16));
    bf16x8 nw1 = ld8((const unsigned short*)(wtmp + (16 + lr) * 80 + lq * 16));
#pragma unroll
    for (int j = 0; j < 16; ++j) {
      if (b == j) { frag0[8 + j] = nw0; frag1[8 + j] = nw1; }
    }
  }

#pragma unroll 1
  for (int ct = 0; ct < 16; ++ct) {
    f32x4 o0 = z, o1 = z;
    const unsigned short* gg = Gout + (size_t)(ct * 16 + lr) * DIMH + koff;
#pragma unroll
    for (int c = 0; c < 24; ++c) {
      bf16x8 bb = ld8(gg + c * 32);
      o0 = mfma16(frag0[c], bb, o0);
      o1 = mfma16(frag1[c], bb, o1);
    }
    float bxv = bx[ct * 16 + lr];
#pragma unroll
    for (int r = 0; r < 4; ++r) {
      out[(size_t)(rowbase + lq * 4 + r) * 256 + ct * 16 + lr] = o0[r] + bxv;
      out[(size_t)(rowbase + 16 + lq * 4 + r) * 256 + ct * 16 + lr] = o1[r] + bxv;
    }
  }
}

extern "C" void kernel_launch(void* const* d_in, const int* in_sizes, int n_in,
                              void* d_out, int out_size, void* d_ws, size_t ws_size,
                              hipStream_t stream) {
  const float* x   = (const float*)d_in[1];
  const float* Pst = (const float*)d_in[2];
  const float* Chi = (const float*)d_in[3];
  const float* X   = (const float*)d_in[4];
  const float* Y1  = (const float*)d_in[5];
  const float* bv  = (const float*)d_in[8];
  const float* bx  = (const float*)d_in[9];
  float* out = (float*)d_out;

  char* ws = (char*)d_ws;
  const size_t OFF_H    = 0;
  const size_t OFF_P    = 2359296;   // P -> L -> Pinv (256KB)
  const size_t OFF_XHI  = 2883584;
  const size_t OFF_XLO  = 4063232;
  const size_t OFF_GIN  = 5242880;
  const size_t OFF_GOUT = 6029312;   // Li (256KB, dead after setup3) -> Gout
  if (ws_size < 6422528) return;

  float* H    = (float*)(ws + OFF_H);
  float* P    = (float*)(ws + OFF_P);
  float* Li   = (float*)(ws + OFF_GOUT);
  unsigned short* Xhi  = (unsigned short*)(ws + OFF_XHI);
  unsigned short* Xlo  = (unsigned short*)(ws + OFF_XLO);
  unsigned short* Gin  = (unsigned short*)(ws + OFF_GIN);
  unsigned short* Gout = (unsigned short*)(ws + OFF_GOUT);

  k_setup1<<<2560, 256, 0, stream>>>(X, Xhi, Xlo, Pst, P);
  k_setup2<<<145, 256, 0, stream>>>(P, Li, Xhi, Xlo, H);
  k_setup3<<<1572, 256, 0, stream>>>(H, Chi, Gin, Li, P);
  dim3 go(24, 8);
  k_gout<<<go, 256, 0, stream>>>(P, H, Y1, Chi, Gout);
  k_main<<<512, 256, SMEM_MAIN, stream>>>(x, Gin, Gout, bv, bx, out);
}